// Round 14
// baseline (539.913 us; speedup 1.0000x reference)
//
#include <hip/hip_runtime.h>
#include <hip/hip_bf16.h>
#include <hip/hip_cooperative_groups.h>

namespace cg = cooperative_groups;

// Shapes (fixed for this problem)
#define BB 2
#define NN 16
#define CC 256
#define KK 64
#define HW 4096
#define NH 8

typedef __attribute__((ext_vector_type(4))) float f32x4;
typedef __attribute__((ext_vector_type(8))) short s16x8;
typedef __attribute__((ext_vector_type(4))) short s16x4;

__device__ __forceinline__ short f2bf(float f) {
    __hip_bfloat16 h = __float2bfloat16(f);
    return *reinterpret_cast<short*>(&h);
}
__device__ __forceinline__ float bf2f(short s) {
    unsigned int u = ((unsigned int)(unsigned short)s) << 16;
    float f; __builtin_memcpy(&f, &u, 4); return f;
}

// ===========================================================================
// Cooperative mega-kernel: all phases, grid 512 x 512 threads (2 blocks/CU).
// smem is a phase-union byte array (80KB -> exactly 2 blocks/CU).
// ===========================================================================
__global__ __launch_bounds__(512, 4) void k_all(
        const float* __restrict__ value, const float* __restrict__ km,
        const float* __restrict__ state, const float* __restrict__ b_w,
        const float* __restrict__ a_w, const float* __restrict__ A_log,
        const float* __restrict__ dt_bias,
        short* __restrict__ kbf, short* __restrict__ kbfT,
        float* __restrict__ gram, float* __restrict__ betaH,
        float* __restrict__ alphaH, short* __restrict__ pbuf,
        float* __restrict__ out) {
    __shared__ __align__(16) char smem[81920];
    const int tid = threadIdx.x;
    const int bid = blockIdx.x;
    cg::grid_group grid = cg::this_grid();

    // ==================== P1: gates (4 ids per block) ====================
    {
        float* redg = (float*)smem;             // 8 waves x 16 floats
        const int half = tid >> 8, ltid = tid & 255;
        const int wave = tid >> 6, lane = tid & 63;
#pragma unroll
        for (int rep = 0; rep < 2; rep++) {
            const int id = bid * 4 + half * 2 + rep;     // 0..2047
            const int bn = id >> 6, k = id & 63;
            const float s = state[((size_t)bn * KK + k) * CC + ltid];
            float pb[NH], pa[NH];
#pragma unroll
            for (int h = 0; h < NH; h++) {
                pb[h] = s * b_w[h * CC + ltid];
                pa[h] = s * a_w[h * CC + ltid];
            }
#pragma unroll
            for (int off = 32; off; off >>= 1) {
#pragma unroll
                for (int h = 0; h < NH; h++) {
                    pb[h] += __shfl_down(pb[h], off, 64);
                    pa[h] += __shfl_down(pa[h], off, 64);
                }
            }
            if (lane == 0) {
#pragma unroll
                for (int h = 0; h < NH; h++) {
                    redg[wave * 16 + h] = pb[h];
                    redg[wave * 16 + 8 + h] = pa[h];
                }
            }
            __syncthreads();
            const int h = ltid >> 5;
            float braw = 0.f, araw = 0.f;
#pragma unroll
            for (int w = 0; w < 4; w++) {
                braw += redg[(half * 4 + w) * 16 + h];
                araw += redg[(half * 4 + w) * 16 + 8 + h];
            }
            if ((ltid & 31) == 0) {
                const float beta = 1.f / (1.f + __expf(-braw));
                const float xx = araw + dt_bias[h];
                const float sp = fmaxf(xx, 0.f) + log1pf(__expf(-fabsf(xx)));
                betaH[(size_t)id * NH + h] = beta;
                alphaH[(size_t)id * NH + h] = -__expf(A_log[h]) * sp;
            }
            __syncthreads();
        }
    }
    // ==================== P1b: softmax (blocks < 32) ====================
    if (bid < 32) {
        const int b = bid >> 4;
        const int wave = tid >> 6, lane = tid & 63;
        const int hw = (bid & 15) * 256 + wave * 32 + (lane & 31);
        const int half = lane >> 5;             // k in [half*32, half*32+32)
        const float* p = km + ((size_t)b * KK + half * 32) * HW + hw;
        float x[32];
        float m = -1e30f;
#pragma unroll
        for (int k = 0; k < 32; k++) { x[k] = p[(size_t)k * HW]; m = fmaxf(m, x[k]); }
        m = fmaxf(m, __shfl_xor(m, 32, 64));
        float s = 0.f;
#pragma unroll
        for (int k = 0; k < 32; k++) { x[k] = __expf(x[k] - m); s += x[k]; }
        s += __shfl_xor(s, 32, 64);
        const float inv = 1.f / s;
        short* q2 = kbf + ((size_t)b * KK + half * 32) * HW + hw;
#pragma unroll
        for (int k = 0; k < 32; k++) {
            x[k] *= inv;
            q2[(size_t)k * HW] = f2bf(x[k]);
        }
        short* q3 = kbfT + ((size_t)b * HW + hw) * KK + half * 32;
#pragma unroll
        for (int k8 = 0; k8 < 32; k8 += 8) {
            s16x8 v;
#pragma unroll
            for (int j = 0; j < 8; j++) v[j] = f2bf(x[k8 + j]);
            *(s16x8*)(q3 + k8) = v;
        }
    }
    __threadfence();
    grid.sync();

    // ==================== P3: gram (2 pairs/block/iter, 5 uniform iters) ==
    {
        float* red3 = (float*)smem;             // 8 floats
        const int half = tid >> 8, ltid = tid & 255;
#pragma unroll 1
        for (int i = 0; i < 5; i++) {
            const int t0 = bid * 2 + half + i * 1024;
            const bool act = (t0 < 2 * 2080);
            int bb = 0, kk2 = 0, jj = 0;
            float s = 0.f;
            if (act) {
                bb = (t0 >= 2080) ? 1 : 0;
                const int t = t0 - bb * 2080;
                int k = (int)((sqrtf(8.f * (float)t + 1.f) - 1.f) * 0.5f);
                while ((k + 1) * (k + 2) / 2 <= t) k++;
                while (k * (k + 1) / 2 > t) k--;
                const int j = t - k * (k + 1) / 2;
                kk2 = k; jj = j;
                const short* pa = kbf + ((size_t)bb * KK + k) * HW + ltid * 16;
                const short* pbp = kbf + ((size_t)bb * KK + j) * HW + ltid * 16;
                const s16x8 a0 = *(const s16x8*)pa, a1 = *(const s16x8*)(pa + 8);
                const s16x8 b0 = *(const s16x8*)pbp, b1 = *(const s16x8*)(pbp + 8);
#pragma unroll
                for (int e = 0; e < 8; e++) {
                    s = fmaf(bf2f(a0[e]), bf2f(b0[e]), s);
                    s = fmaf(bf2f(a1[e]), bf2f(b1[e]), s);
                }
            }
#pragma unroll
            for (int off = 32; off; off >>= 1) s += __shfl_down(s, off, 64);
            if ((tid & 63) == 0) red3[tid >> 6] = s;
            __syncthreads();
            if (act && ltid == 0) {
                const float tot = red3[half * 4] + red3[half * 4 + 1] +
                                  red3[half * 4 + 2] + red3[half * 4 + 3];
                gram[((size_t)bb * KK + kk2) * KK + jj] = tot;
                gram[((size_t)bb * KK + jj) * KK + kk2] = tot;
            }
            __syncthreads();
        }
    }
    __threadfence();
    grid.sync();

    // ==================== P5: vkt split-K (r12 body) ====================
    {
        short* BsP = (short*)smem;              // [2][16384]  64KB
        short* AsP = (short*)(smem + 65536);    // [2][4096]   16KB
        const int id = bid;                     // bn*16 + hs
        const int hs = id & 15;
        const int bn = id >> 4;
        const int b  = bn >> 4;
        const int w = tid >> 6, lane = tid & 63;
        const int l15 = lane & 15, hi = lane >> 4;
        const int hw0 = hs * 256;

        const int sr = tid >> 3;                // 0..63
        const int sj = tid & 7;                 // 0..7
        const float* vbase = value + (size_t)bn * CC * HW + hw0;
        const short* abase = kbf + ((size_t)b * KK + sr) * HW + hw0 + sj * 8;

        f32x4 stgB[2][4][2];
        s16x8 stgA[2];

#define LOADREG(set_, t_)                                                      \
    {                                                                          \
        _Pragma("unroll") for (int i = 0; i < 4; i++) {                        \
            const float* p_ = vbase + (size_t)(sr + i * 64) * HW               \
                              + (t_) * 64 + sj * 8;                            \
            stgB[set_][i][0] = *(const f32x4*)p_;                              \
            stgB[set_][i][1] = *(const f32x4*)(p_ + 4);                        \
        }                                                                      \
        stgA[set_] = *(const s16x8*)(abase + (t_) * 64);                       \
    }
#define WRITE_LDS(set_, buf_)                                                  \
    {                                                                          \
        _Pragma("unroll") for (int i = 0; i < 4; i++) {                        \
            const int r_ = sr + i * 64;                                        \
            s16x8 tv_;                                                         \
            _Pragma("unroll") for (int e = 0; e < 4; e++) {                    \
                tv_[e]     = f2bf(stgB[set_][i][0][e]);                        \
                tv_[4 + e] = f2bf(stgB[set_][i][1][e]);                        \
            }                                                                  \
            *(s16x8*)&BsP[(buf_) * 16384 + r_ * 64 + ((sj ^ (r_ & 7)) * 8)] = tv_; \
        }                                                                      \
        *(s16x8*)&AsP[(buf_) * 4096 + sr * 64 + ((sj ^ (sr & 7)) * 8)] = stgA[set_]; \
    }

        f32x4 acc[2][4];
#pragma unroll
        for (int m2 = 0; m2 < 2; m2++)
#pragma unroll
            for (int n4 = 0; n4 < 4; n4++) acc[m2][n4] = (f32x4){0.f, 0.f, 0.f, 0.f};

        LOADREG(0, 0);
        LOADREG(1, 1);
        WRITE_LDS(0, 0);
        asm volatile("s_waitcnt lgkmcnt(0)" ::: "memory");
        __builtin_amdgcn_s_barrier();

#pragma unroll
        for (int t = 0; t < 4; t++) {
            const int buf = t & 1;
            if (t + 2 < 4) LOADREG(buf, t + 2);
            if (t + 1 < 4) WRITE_LDS((t + 1) & 1, (t + 1) & 1);

            const int swz = l15 & 7;
#pragma unroll
            for (int s = 0; s < 2; s++) {
                s16x8 vfr[2];
#pragma unroll
                for (int m2 = 0; m2 < 2; m2++)
                    vfr[m2] = *(const s16x8*)&BsP[buf * 16384 +
                                                  (w * 32 + m2 * 16 + l15) * 64 +
                                                  (((s * 4 + hi) ^ swz) * 8)];
#pragma unroll
                for (int n4 = 0; n4 < 4; n4++) {
                    const s16x8 afr = *(const s16x8*)&AsP[buf * 4096 +
                                                          (n4 * 16 + l15) * 64 +
                                                          (((s * 4 + hi) ^ swz) * 8)];
                    acc[0][n4] = __builtin_amdgcn_mfma_f32_16x16x32_bf16(vfr[0], afr,
                                                                         acc[0][n4], 0, 0, 0);
                    acc[1][n4] = __builtin_amdgcn_mfma_f32_16x16x32_bf16(vfr[1], afr,
                                                                         acc[1][n4], 0, 0, 0);
                }
            }
            if (t + 1 < 4) {
                asm volatile("s_waitcnt lgkmcnt(0)" ::: "memory");
                __builtin_amdgcn_s_barrier();
            }
        }
#undef LOADREG
#undef WRITE_LDS

#pragma unroll
        for (int m2 = 0; m2 < 2; m2++)
#pragma unroll
            for (int n4 = 0; n4 < 4; n4++) {
                s16x4 v;
#pragma unroll
                for (int r = 0; r < 4; r++) v[r] = f2bf(acc[m2][n4][r]);
                *(s16x4*)(pbuf + ((((size_t)(id * 8 + w) * 2 + m2) * 4 + n4) * 64
                                  + lane) * 4) = v;
            }
    }
    __threadfence();
    grid.sync();

    // ==================== P7: combine + readout (r13 k_cr) ==============
    {
        float* gramL = (float*)smem;                 // [64][65]
        float* stL   = (float*)(smem + 16640);       // [64][17]
        float* alphaL= (float*)(smem + 20992);       // [64]
        float* betaL = (float*)(smem + 21248);       // [64]
        float* nsb   = (float*)(smem + 21504);       // [64][17]
        short* nsB   = (short*)(smem + 25856);       // [16][72]

        const int ct = bid & 15;
        const int bn = bid >> 4;
        const int b  = bn >> 4;
        const int head = ct >> 1;
        const int wi = ct >> 1, m2 = ct & 1;

        for (int i = tid; i < KK * KK; i += 512)
            gramL[(i >> 6) * 65 + (i & 63)] = gram[(size_t)b * KK * KK + i];
        for (int i = tid; i < KK * 16; i += 512)
            stL[(i >> 4) * 17 + (i & 15)] =
                state[((size_t)bn * KK + (i >> 4)) * CC + ct * 16 + (i & 15)];
        if (tid < KK) {
            alphaL[tid] = alphaH[((size_t)bn * KK + tid) * NH + head];
            betaL[tid]  = betaH[((size_t)bn * KK + tid) * NH + head];
        }
        __syncthreads();

        if (tid < 256) {
            const int k = tid >> 2, cq = (tid & 3) * 4;
            const int n4 = k >> 4, l15k = k & 15, hi4 = tid & 3;

            float vkt[4] = {0.f, 0.f, 0.f, 0.f};
#pragma unroll
            for (int hs = 0; hs < 16; hs++) {
                const int slab = bn * 16 + hs;
                const s16x4 p = *(const s16x4*)(pbuf +
                    ((((size_t)(slab * 8 + wi) * 2 + m2) * 4 + n4) * 64 +
                     hi4 * 16 + l15k) * 4);
#pragma unroll
                for (int i = 0; i < 4; i++) vkt[i] += bf2f(p[i]);
            }

            float vk[4] = {0.f, 0.f, 0.f, 0.f};
#pragma unroll 8
            for (int j = 0; j < KK; j++) {
                const float g = gramL[k * 65 + j];
                vk[0] = fmaf(g, stL[j * 17 + cq + 0], vk[0]);
                vk[1] = fmaf(g, stL[j * 17 + cq + 1], vk[1]);
                vk[2] = fmaf(g, stL[j * 17 + cq + 2], vk[2]);
                vk[3] = fmaf(g, stL[j * 17 + cq + 3], vk[3]);
            }
            const float al = alphaL[k], be = betaL[k];
#pragma unroll
            for (int i = 0; i < 4; i++)
                nsb[k * 17 + cq + i] =
                    al * (stL[k * 17 + cq + i] - be * vk[i]) + be * vkt[i];
        }
        __syncthreads();

        if (tid < 256) {
            const int c = tid >> 4, k4 = (tid & 15) * 4;
            s16x4 v;
#pragma unroll
            for (int i = 0; i < 4; i++) v[i] = f2bf(nsb[(k4 + i) * 17 + c]);
            *(s16x4*)&nsB[c * 72 + k4] = v;
        }
        __syncthreads();

        const int w8 = tid >> 6, lane = tid & 63;
        const int l15 = lane & 15, hi = lane >> 4;

        const s16x8 cf0 = *(const s16x8*)&nsB[l15 * 72 + hi * 8];
        const s16x8 cf1 = *(const s16x8*)&nsB[l15 * 72 + 32 + hi * 8];

        const short* kb = kbfT + ((size_t)b * HW + l15) * KK + hi * 8;
        float* ob = out + ((size_t)bn * CC + ct * 16 + l15) * HW + hi * 4;

#pragma unroll 4
        for (int mt = 0; mt < 32; mt++) {
            const int hw0 = mt * 128 + w8 * 16;
            const short* Bp = kb + (size_t)hw0 * KK;
            const s16x8 hwf0 = *(const s16x8*)Bp;
            const s16x8 hwf1 = *(const s16x8*)(Bp + 32);
            f32x4 acc = (f32x4){0.f, 0.f, 0.f, 0.f};
            acc = __builtin_amdgcn_mfma_f32_16x16x32_bf16(hwf0, cf0, acc, 0, 0, 0);
            acc = __builtin_amdgcn_mfma_f32_16x16x32_bf16(hwf1, cf1, acc, 0, 0, 0);
            *(f32x4*)(ob + hw0) = acc;
        }
    }
}

// ===========================================================================
// Fallback path (r13, 4 launches) — used if cooperative launch unavailable.
// ===========================================================================
__global__ __launch_bounds__(256) void k_pre(const float* __restrict__ state,
                                             const float* __restrict__ b_w,
                                             const float* __restrict__ a_w,
                                             const float* __restrict__ A_log,
                                             const float* __restrict__ dt_bias,
                                             float* __restrict__ betaH,
                                             float* __restrict__ alphaH,
                                             const float* __restrict__ km,
                                             short* __restrict__ kbf,
                                             short* __restrict__ kbfT) {
    __shared__ float red[4][2 * NH];
    const int tid = threadIdx.x;
    const int bid = blockIdx.x;

    if (bid < BB * NN * KK) {
        const int id = bid;
        const int bn = id >> 6;
        const int k = id & 63;
        const float s = state[((size_t)bn * KK + k) * CC + tid];

        float pb[NH], pa[NH];
#pragma unroll
        for (int h = 0; h < NH; h++) {
            pb[h] = s * b_w[h * CC + tid];
            pa[h] = s * a_w[h * CC + tid];
        }
#pragma unroll
        for (int off = 32; off; off >>= 1) {
#pragma unroll
            for (int h = 0; h < NH; h++) {
                pb[h] += __shfl_down(pb[h], off, 64);
                pa[h] += __shfl_down(pa[h], off, 64);
            }
        }
        const int wave = tid >> 6, lane = tid & 63;
        if (lane == 0) {
#pragma unroll
            for (int h = 0; h < NH; h++) { red[wave][h] = pb[h]; red[wave][NH + h] = pa[h]; }
        }
        __syncthreads();
        const int h = tid >> 5;
        float braw = 0.f, araw = 0.f;
#pragma unroll
        for (int w = 0; w < 4; w++) { braw += red[w][h]; araw += red[w][NH + h]; }
        if ((tid & 31) == 0) {
            const float beta = 1.f / (1.f + __expf(-braw));
            const float xx = araw + dt_bias[h];
            const float sp = fmaxf(xx, 0.f) + log1pf(__expf(-fabsf(xx)));
            betaH[(size_t)id * NH + h] = beta;
            alphaH[(size_t)id * NH + h] = -__expf(A_log[h]) * sp;
        }
    } else {
        const int sid = bid - BB * NN * KK;
        const int b = sid >> 5;
        const int w = tid >> 6, lane = tid & 63;
        const int hw = (sid & 31) * 128 + w * 32 + (lane & 31);
        const int half = lane >> 5;
        const float* p = km + ((size_t)b * KK + half * 32) * HW + hw;
        float x[32];
        float m = -1e30f;
#pragma unroll
        for (int k = 0; k < 32; k++) { x[k] = p[(size_t)k * HW]; m = fmaxf(m, x[k]); }
        m = fmaxf(m, __shfl_xor(m, 32, 64));
        float s = 0.f;
#pragma unroll
        for (int k = 0; k < 32; k++) { x[k] = __expf(x[k] - m); s += x[k]; }
        s += __shfl_xor(s, 32, 64);
        const float inv = 1.f / s;
        short* q2 = kbf + ((size_t)b * KK + half * 32) * HW + hw;
#pragma unroll
        for (int k = 0; k < 32; k++) {
            x[k] *= inv;
            q2[(size_t)k * HW] = f2bf(x[k]);
        }
        short* q3 = kbfT + ((size_t)b * HW + hw) * KK + half * 32;
#pragma unroll
        for (int k8 = 0; k8 < 32; k8 += 8) {
            s16x8 v;
#pragma unroll
            for (int j = 0; j < 8; j++) v[j] = f2bf(x[k8 + j]);
            *(s16x8*)(q3 + k8) = v;
        }
    }
}

__global__ __launch_bounds__(256) void k_gram(const short* __restrict__ kbf,
                                              float* __restrict__ gram) {
    const int tid = threadIdx.x;
    const int id = blockIdx.x;
    const int b = (id >= 2080) ? 1 : 0;
    const int t = id - b * 2080;
    int k = (int)((sqrtf(8.f * (float)t + 1.f) - 1.f) * 0.5f);
    while ((k + 1) * (k + 2) / 2 <= t) k++;
    while (k * (k + 1) / 2 > t) k--;
    const int j = t - k * (k + 1) / 2;

    const short* pa = kbf + ((size_t)b * KK + k) * HW + tid * 16;
    const short* pb = kbf + ((size_t)b * KK + j) * HW + tid * 16;
    const s16x8 a0 = *(const s16x8*)pa, a1 = *(const s16x8*)(pa + 8);
    const s16x8 b0 = *(const s16x8*)pb, b1 = *(const s16x8*)(pb + 8);
    float s = 0.f;
#pragma unroll
    for (int i = 0; i < 8; i++) {
        s = fmaf(bf2f(a0[i]), bf2f(b0[i]), s);
        s = fmaf(bf2f(a1[i]), bf2f(b1[i]), s);
    }
#pragma unroll
    for (int off = 32; off; off >>= 1) s += __shfl_down(s, off, 64);
    __shared__ float red[4];
    if ((tid & 63) == 0) red[tid >> 6] = s;
    __syncthreads();
    if (tid == 0) {
        const float tot = red[0] + red[1] + red[2] + red[3];
        gram[((size_t)b * KK + k) * KK + j] = tot;
        gram[((size_t)b * KK + j) * KK + k] = tot;
    }
}

__global__ __launch_bounds__(512) void k_vkt_part(const short* __restrict__ kbf,
                                                  const float* __restrict__ value,
                                                  short* __restrict__ pbuf) {
    const int tid = threadIdx.x;
    const int id = blockIdx.x;
    const int hs = id & 15;
    const int bn = id >> 4;
    const int b  = bn >> 4;
    const int w = tid >> 6, lane = tid & 63;
    const int l15 = lane & 15, hi = lane >> 4;
    const int hw0 = hs * 256;

    __shared__ short Bs[2][256 * 64];
    __shared__ short As[2][64 * 64];

    const int sr = tid >> 3;
    const int sj = tid & 7;
    const float* vbase = value + (size_t)bn * CC * HW + hw0;
    const short* abase = kbf + ((size_t)b * KK + sr) * HW + hw0 + sj * 8;

    f32x4 stgB[2][4][2];
    s16x8 stgA[2];

#define LOADREG(set_, t_)                                                      \
    {                                                                          \
        _Pragma("unroll") for (int i = 0; i < 4; i++) {                        \
            const float* p_ = vbase + (size_t)(sr + i * 64) * HW               \
                              + (t_) * 64 + sj * 8;                            \
            stgB[set_][i][0] = *(const f32x4*)p_;                              \
            stgB[set_][i][1] = *(const f32x4*)(p_ + 4);                        \
        }                                                                      \
        stgA[set_] = *(const s16x8*)(abase + (t_) * 64);                       \
    }
#define WRITE_LDS(set_, buf_)                                                  \
    {                                                                          \
        _Pragma("unroll") for (int i = 0; i < 4; i++) {                        \
            const int r_ = sr + i * 64;                                        \
            s16x8 tv_;                                                         \
            _Pragma("unroll") for (int e = 0; e < 4; e++) {                    \
                tv_[e]     = f2bf(stgB[set_][i][0][e]);                        \
                tv_[4 + e] = f2bf(stgB[set_][i][1][e]);                        \
            }                                                                  \
            *(s16x8*)&Bs[buf_][r_ * 64 + ((sj ^ (r_ & 7)) * 8)] = tv_;         \
        }                                                                      \
        *(s16x8*)&As[buf_][sr * 64 + ((sj ^ (sr & 7)) * 8)] = stgA[set_];      \
    }

    f32x4 acc[2][4];
#pragma unroll
    for (int m2 = 0; m2 < 2; m2++)
#pragma unroll
        for (int n4 = 0; n4 < 4; n4++) acc[m2][n4] = (f32x4){0.f, 0.f, 0.f, 0.f};

    LOADREG(0, 0);
    LOADREG(1, 1);
    WRITE_LDS(0, 0);
    asm volatile("s_waitcnt lgkmcnt(0)" ::: "memory");
    __builtin_amdgcn_s_barrier();

#pragma unroll
    for (int t = 0; t < 4; t++) {
        const int buf = t & 1;
        if (t + 2 < 4) LOADREG(buf, t + 2);
        if (t + 1 < 4) WRITE_LDS((t + 1) & 1, (t + 1) & 1);

        const int swz = l15 & 7;
#pragma unroll
        for (int s = 0; s < 2; s++) {
            s16x8 vfr[2];
#pragma unroll
            for (int m2 = 0; m2 < 2; m2++)
                vfr[m2] = *(const s16x8*)&Bs[buf][(w * 32 + m2 * 16 + l15) * 64 +
                                                 (((s * 4 + hi) ^ swz) * 8)];
#pragma unroll
            for (int n4 = 0; n4 < 4; n4++) {
                const s16x8 afr = *(const s16x8*)&As[buf][(n4 * 16 + l15) * 64 +
                                                          (((s * 4 + hi) ^ swz) * 8)];
                acc[0][n4] = __builtin_amdgcn_mfma_f32_16x16x32_bf16(vfr[0], afr,
                                                                     acc[0][n4], 0, 0, 0);
                acc[1][n4] = __builtin_amdgcn_mfma_f32_16x16x32_bf16(vfr[1], afr,
                                                                     acc[1][n4], 0, 0, 0);
            }
        }
        if (t + 1 < 4) {
            asm volatile("s_waitcnt lgkmcnt(0)" ::: "memory");
            __builtin_amdgcn_s_barrier();
        }
    }
#undef LOADREG
#undef WRITE_LDS

#pragma unroll
    for (int m2 = 0; m2 < 2; m2++)
#pragma unroll
        for (int n4 = 0; n4 < 4; n4++) {
            s16x4 v;
#pragma unroll
            for (int r = 0; r < 4; r++) v[r] = f2bf(acc[m2][n4][r]);
            *(s16x4*)(pbuf + ((((size_t)(id * 8 + w) * 2 + m2) * 4 + n4) * 64
                              + lane) * 4) = v;
        }
}

__global__ __launch_bounds__(256) void k_cr(const short* __restrict__ pbuf,
                                            const float* __restrict__ gram,
                                            const float* __restrict__ state,
                                            const float* __restrict__ betaH,
                                            const float* __restrict__ alphaH,
                                            const short* __restrict__ kbfT,
                                            float* __restrict__ out) {
    const int tid = threadIdx.x;
    const int id = blockIdx.x;
    const int ct = id & 15;
    const int bn = id >> 4;
    const int b  = bn >> 4;
    const int head = ct >> 1;
    const int wi = ct >> 1, m2 = ct & 1;

    __shared__ float gramL[KK][65];
    __shared__ float stL[KK][17];
    __shared__ float alphaL[KK], betaL[KK];
    __shared__ float nsb[KK][17];
    __shared__ short nsB[16][72];

    for (int i = tid; i < KK * KK; i += 256)
        gramL[i >> 6][i & 63] = gram[(size_t)b * KK * KK + i];
    for (int i = tid; i < KK * 16; i += 256)
        stL[i >> 4][i & 15] = state[((size_t)bn * KK + (i >> 4)) * CC + ct * 16 + (i & 15)];
    if (tid < KK) {
        alphaL[tid] = alphaH[((size_t)bn * KK + tid) * NH + head];
        betaL[tid]  = betaH[((size_t)bn * KK + tid) * NH + head];
    }
    __syncthreads();

    {
        const int k = tid >> 2, cq = (tid & 3) * 4;
        const int n4 = k >> 4, l15k = k & 15, hi4 = tid & 3;

        float vkt[4] = {0.f, 0.f, 0.f, 0.f};
#pragma unroll
        for (int hs = 0; hs < 16; hs++) {
            const int slab = bn * 16 + hs;
            const s16x4 p = *(const s16x4*)(pbuf +
                ((((size_t)(slab * 8 + wi) * 2 + m2) * 4 + n4) * 64 + hi4 * 16 + l15k) * 4);
#pragma unroll
            for (int i = 0; i < 4; i++) vkt[i] += bf2f(p[i]);
        }

        float vk[4] = {0.f, 0.f, 0.f, 0.f};
#pragma unroll 8
        for (int j = 0; j < KK; j++) {
            const float g = gramL[k][j];
            vk[0] = fmaf(g, stL[j][cq + 0], vk[0]);
            vk[1] = fmaf(g, stL[j][cq + 1], vk[1]);
            vk[2] = fmaf(g, stL[j][cq + 2], vk[2]);
            vk[3] = fmaf(g, stL[j][cq + 3], vk[3]);
        }
        const float al = alphaL[k], be = betaL[k];
#pragma unroll
        for (int i = 0; i < 4; i++)
            nsb[k][cq + i] = al * (stL[k][cq + i] - be * vk[i]) + be * vkt[i];
    }
    __syncthreads();

    {
        const int c = tid >> 4, k4 = (tid & 15) * 4;
        s16x4 v;
#pragma unroll
        for (int i = 0; i < 4; i++) v[i] = f2bf(nsb[k4 + i][c]);
        *(s16x4*)&nsB[c][k4] = v;
    }
    __syncthreads();

    const int w = tid >> 6, lane = tid & 63;
    const int l15 = lane & 15, hi = lane >> 4;

    const s16x8 cf0 = *(const s16x8*)&nsB[l15][hi * 8];
    const s16x8 cf1 = *(const s16x8*)&nsB[l15][32 + hi * 8];

    const short* kb = kbfT + ((size_t)b * HW + l15) * KK + hi * 8;
    float* ob = out + ((size_t)bn * CC + ct * 16 + l15) * HW + hi * 4;

#pragma unroll 4
    for (int mt = 0; mt < 64; mt++) {
        const int hw0 = mt * 64 + w * 16;
        const short* Bp = kb + (size_t)hw0 * KK;
        const s16x8 hwf0 = *(const s16x8*)Bp;
        const s16x8 hwf1 = *(const s16x8*)(Bp + 32);
        f32x4 acc = (f32x4){0.f, 0.f, 0.f, 0.f};
        acc = __builtin_amdgcn_mfma_f32_16x16x32_bf16(hwf0, cf0, acc, 0, 0, 0);
        acc = __builtin_amdgcn_mfma_f32_16x16x32_bf16(hwf1, cf1, acc, 0, 0, 0);
        *(f32x4*)(ob + hw0) = acc;
    }
}

// ---------------------------------------------------------------------------
extern "C" void kernel_launch(void* const* d_in, const int* in_sizes, int n_in,
                              void* d_out, int out_size, void* d_ws, size_t ws_size,
                              hipStream_t stream) {
    const float* value   = (const float*)d_in[0];
    const float* key_map = (const float*)d_in[1];
    const float* state   = (const float*)d_in[2];
    const float* b_w     = (const float*)d_in[3];
    const float* a_w     = (const float*)d_in[4];
    const float* A_log   = (const float*)d_in[5];
    const float* dt_bias = (const float*)d_in[6];
    float* out = (float*)d_out;

    short* kbf   = (short*)d_ws;              // B*K*HW bf16     = 524288 sh
    short* kbfT  = kbf + 524288;              // B*HW*K bf16     = 524288 sh
    float* gram  = (float*)(kbfT + 524288);   // B*K*K           =   8192 f32
    float* betaH = gram + 8192;               // B*N*K*NH        =  16384 f32
    float* alphaH= betaH + 16384;             // B*N*K*NH        =  16384 f32
    short* pbufB = (short*)(alphaH + 16384);  // 512*16384 bf16  = 16 MB

    void* kargs[] = {(void*)&value, (void*)&key_map, (void*)&state,
                     (void*)&b_w, (void*)&a_w, (void*)&A_log, (void*)&dt_bias,
                     (void*)&kbf, (void*)&kbfT, (void*)&gram,
                     (void*)&betaH, (void*)&alphaH, (void*)&pbufB, (void*)&out};
    hipError_t err = hipLaunchCooperativeKernel((void*)k_all, dim3(512), dim3(512),
                                                kargs, 0, stream);
    if (err != hipSuccess) {
        // Fallback: r13 4-launch path (identical numerics).
        k_pre<<<BB * NN * KK + BB * (HW / 128), 256, 0, stream>>>(
            state, b_w, a_w, A_log, dt_bias, betaH, alphaH, key_map, kbf, kbfT);
        k_gram<<<BB * (KK * (KK + 1) / 2), 256, 0, stream>>>(kbf, gram);
        k_vkt_part<<<BB * NN * 16, 512, 0, stream>>>(kbf, value, pbufB);
        k_cr<<<BB * NN * 16, 256, 0, stream>>>(pbufB, gram, state, betaH, alphaH,
                                               kbfT, out);
    }
}

// Round 15
// 107.174 us; speedup vs baseline: 5.0377x; 5.0377x over previous
//
#include <hip/hip_runtime.h>
#include <hip/hip_bf16.h>

// Shapes (fixed for this problem)
#define BB 2
#define NN 16
#define CC 256
#define KK 64
#define HW 4096
#define NH 8

typedef __attribute__((ext_vector_type(4))) float f32x4;
typedef __attribute__((ext_vector_type(8))) short s16x8;
typedef __attribute__((ext_vector_type(4))) short s16x4;

__device__ __forceinline__ short f2bf(float f) {
    __hip_bfloat16 h = __float2bfloat16(f);
    return *reinterpret_cast<short*>(&h);
}
__device__ __forceinline__ float bf2f(short s) {
    unsigned int u = ((unsigned int)(unsigned short)s) << 16;
    float f; __builtin_memcpy(&f, &u, 4); return f;
}

// ---------------------------------------------------------------------------
// K1 (fused): blocks [0,2048) = gates (beta/alpha per (b,n,k,h));
//             blocks [2048,2112) = softmax over K (emits kbf, kbfT).
// ---------------------------------------------------------------------------
__global__ __launch_bounds__(256) void k_pre(const float* __restrict__ state,
                                             const float* __restrict__ b_w,
                                             const float* __restrict__ a_w,
                                             const float* __restrict__ A_log,
                                             const float* __restrict__ dt_bias,
                                             float* __restrict__ betaH,
                                             float* __restrict__ alphaH,
                                             const float* __restrict__ km,
                                             short* __restrict__ kbf,
                                             short* __restrict__ kbfT) {
    __shared__ float red[4][2 * NH];
    const int tid = threadIdx.x;
    const int bid = blockIdx.x;

    if (bid < BB * NN * KK) {
        // ---------------- gates ----------------
        const int id = bid;            // (b*N+n)*K + k
        const int bn = id >> 6;
        const int k = id & 63;
        const float s = state[((size_t)bn * KK + k) * CC + tid];

        float pb[NH], pa[NH];
#pragma unroll
        for (int h = 0; h < NH; h++) {
            pb[h] = s * b_w[h * CC + tid];
            pa[h] = s * a_w[h * CC + tid];
        }
#pragma unroll
        for (int off = 32; off; off >>= 1) {
#pragma unroll
            for (int h = 0; h < NH; h++) {
                pb[h] += __shfl_down(pb[h], off, 64);
                pa[h] += __shfl_down(pa[h], off, 64);
            }
        }
        const int wave = tid >> 6, lane = tid & 63;
        if (lane == 0) {
#pragma unroll
            for (int h = 0; h < NH; h++) { red[wave][h] = pb[h]; red[wave][NH + h] = pa[h]; }
        }
        __syncthreads();
        const int h = tid >> 5;
        float braw = 0.f, araw = 0.f;
#pragma unroll
        for (int w = 0; w < 4; w++) { braw += red[w][h]; araw += red[w][NH + h]; }
        if ((tid & 31) == 0) {
            const float beta = 1.f / (1.f + __expf(-braw));
            const float xx = araw + dt_bias[h];
            const float sp = fmaxf(xx, 0.f) + log1pf(__expf(-fabsf(xx)));
            betaH[(size_t)id * NH + h] = beta;
            alphaH[(size_t)id * NH + h] = -__expf(A_log[h]) * sp;
        }
    } else {
        // ---------------- softmax (128 hw per block) ----------------
        const int sid = bid - BB * NN * KK;     // 0..63
        const int b = sid >> 5;                 // 32 blocks per b
        const int w = tid >> 6, lane = tid & 63;
        const int hw = (sid & 31) * 128 + w * 32 + (lane & 31);
        const int half = lane >> 5;             // k in [half*32, half*32+32)
        const float* p = km + ((size_t)b * KK + half * 32) * HW + hw;
        float x[32];
        float m = -1e30f;
#pragma unroll
        for (int k = 0; k < 32; k++) { x[k] = p[(size_t)k * HW]; m = fmaxf(m, x[k]); }
        m = fmaxf(m, __shfl_xor(m, 32, 64));
        float s = 0.f;
#pragma unroll
        for (int k = 0; k < 32; k++) { x[k] = __expf(x[k] - m); s += x[k]; }
        s += __shfl_xor(s, 32, 64);
        const float inv = 1.f / s;
        short* q2 = kbf + ((size_t)b * KK + half * 32) * HW + hw;
#pragma unroll
        for (int k = 0; k < 32; k++) {
            x[k] *= inv;
            q2[(size_t)k * HW] = f2bf(x[k]);
        }
        short* q3 = kbfT + ((size_t)b * HW + hw) * KK + half * 32;
#pragma unroll
        for (int k8 = 0; k8 < 32; k8 += 8) {
            s16x8 v;
#pragma unroll
            for (int j = 0; j < 8; j++) v[j] = f2bf(x[k8 + j]);
            *(s16x8*)(q3 + k8) = v;
        }
    }
}

// ---------------------------------------------------------------------------
// K4a (MFMA, split-K): partial vkt[k, all 256 c] per 256-hw slab, PLUS a
// gram tail (9 symmetric pairs per block; k_gram launch eliminated).
// Grid = bn(32) x hs(16) = 512 blocks, 512 threads (8 waves).
// Single barrier per iteration; bf16 partials, store-order-native layout,
// chunk radix 8. (Main loop unchanged from r12/r13 — debugged & passing.)
// ---------------------------------------------------------------------------
__global__ __launch_bounds__(512) void k_vkt_part(const short* __restrict__ kbf,
                                                  const float* __restrict__ value,
                                                  short* __restrict__ pbuf,
                                                  float* __restrict__ gram) {
    const int tid = threadIdx.x;
    const int id = blockIdx.x;          // bn*16 + hs
    const int hs = id & 15;
    const int bn = id >> 4;
    const int b  = bn >> 4;
    const int w = tid >> 6, lane = tid & 63;
    const int l15 = lane & 15, hi = lane >> 4;
    const int hw0 = hs * 256;

    __shared__ short Bs[2][256 * 64];   // value tile bf16, 32KB per buffer
    __shared__ short As[2][64 * 64];    // kbf  tile bf16,  8KB per buffer

    const int sr = tid >> 3;            // 0..63
    const int sj = tid & 7;             // 0..7
    const float* vbase = value + (size_t)bn * CC * HW + hw0;
    const short* abase = kbf + ((size_t)b * KK + sr) * HW + hw0 + sj * 8;

    f32x4 stgB[2][4][2];
    s16x8 stgA[2];

#define LOADREG(set_, t_)                                                      \
    {                                                                          \
        _Pragma("unroll") for (int i = 0; i < 4; i++) {                        \
            const float* p_ = vbase + (size_t)(sr + i * 64) * HW               \
                              + (t_) * 64 + sj * 8;                            \
            stgB[set_][i][0] = *(const f32x4*)p_;                              \
            stgB[set_][i][1] = *(const f32x4*)(p_ + 4);                        \
        }                                                                      \
        stgA[set_] = *(const s16x8*)(abase + (t_) * 64);                       \
    }
#define WRITE_LDS(set_, buf_)                                                  \
    {                                                                          \
        _Pragma("unroll") for (int i = 0; i < 4; i++) {                        \
            const int r_ = sr + i * 64;                                        \
            s16x8 tv_;                                                         \
            _Pragma("unroll") for (int e = 0; e < 4; e++) {                    \
                tv_[e]     = f2bf(stgB[set_][i][0][e]);                        \
                tv_[4 + e] = f2bf(stgB[set_][i][1][e]);                        \
            }                                                                  \
            *(s16x8*)&Bs[buf_][r_ * 64 + ((sj ^ (r_ & 7)) * 8)] = tv_;         \
        }                                                                      \
        *(s16x8*)&As[buf_][sr * 64 + ((sj ^ (sr & 7)) * 8)] = stgA[set_];      \
    }

    f32x4 acc[2][4];                    // [c-tile m2][k-tile n4]
#pragma unroll
    for (int m2 = 0; m2 < 2; m2++)
#pragma unroll
        for (int n4 = 0; n4 < 4; n4++) acc[m2][n4] = (f32x4){0.f, 0.f, 0.f, 0.f};

    // prologue
    LOADREG(0, 0);
    LOADREG(1, 1);
    WRITE_LDS(0, 0);
    asm volatile("s_waitcnt lgkmcnt(0)" ::: "memory");
    __builtin_amdgcn_s_barrier();

#pragma unroll
    for (int t = 0; t < 4; t++) {
        const int buf = t & 1;
        if (t + 2 < 4) LOADREG(buf, t + 2);          // HBM prefetch, 2 ahead
        if (t + 1 < 4) WRITE_LDS((t + 1) & 1, (t + 1) & 1);  // stage NEXT buffer

        const int swz = l15 & 7;
#pragma unroll
        for (int s = 0; s < 2; s++) {
            s16x8 vfr[2];
#pragma unroll
            for (int m2 = 0; m2 < 2; m2++)
                vfr[m2] = *(const s16x8*)&Bs[buf][(w * 32 + m2 * 16 + l15) * 64 +
                                                 (((s * 4 + hi) ^ swz) * 8)];
#pragma unroll
            for (int n4 = 0; n4 < 4; n4++) {
                const s16x8 afr = *(const s16x8*)&As[buf][(n4 * 16 + l15) * 64 +
                                                          (((s * 4 + hi) ^ swz) * 8)];
                acc[0][n4] = __builtin_amdgcn_mfma_f32_16x16x32_bf16(vfr[0], afr,
                                                                     acc[0][n4], 0, 0, 0);
                acc[1][n4] = __builtin_amdgcn_mfma_f32_16x16x32_bf16(vfr[1], afr,
                                                                     acc[1][n4], 0, 0, 0);
            }
        }
        if (t + 1 < 4) {
            asm volatile("s_waitcnt lgkmcnt(0)" ::: "memory");
            __builtin_amdgcn_s_barrier();            // single barrier per iter
        }
    }
#undef LOADREG
#undef WRITE_LDS

    // bf16 partial, store-order-native layout, chunk radix 8 (8 waves)
#pragma unroll
    for (int m2 = 0; m2 < 2; m2++)
#pragma unroll
        for (int n4 = 0; n4 < 4; n4++) {
            s16x4 v;
#pragma unroll
            for (int r = 0; r < 4; r++) v[r] = f2bf(acc[m2][n4][r]);
            *(s16x4*)(pbuf + ((((size_t)(id * 8 + w) * 2 + m2) * 4 + n4) * 64
                              + lane) * 4) = v;
        }

    // ---- gram tail: pairs t0 = id + i*512, i = 0..8 (covers 2*2080 = 4160).
    // Each pair: full 4096-hw dot, 8 bf16/thread (tid*8), wave+LDS reduce.
    __syncthreads();
    __shared__ float redG[8];
#pragma unroll 1
    for (int i = 0; i < 9; i++) {
        const int t0 = id + i * 512;
        if (t0 >= 2 * 2080) break;               // block-uniform
        const int bb = (t0 >= 2080) ? 1 : 0;
        const int t = t0 - bb * 2080;
        int k = (int)((sqrtf(8.f * (float)t + 1.f) - 1.f) * 0.5f);
        while ((k + 1) * (k + 2) / 2 <= t) k++;
        while (k * (k + 1) / 2 > t) k--;
        const int j = t - k * (k + 1) / 2;

        const short* pa = kbf + ((size_t)bb * KK + k) * HW + tid * 8;
        const short* pbp = kbf + ((size_t)bb * KK + j) * HW + tid * 8;
        const s16x8 a0 = *(const s16x8*)pa;
        const s16x8 b0 = *(const s16x8*)pbp;
        float s = 0.f;
#pragma unroll
        for (int e = 0; e < 8; e++) s = fmaf(bf2f(a0[e]), bf2f(b0[e]), s);
#pragma unroll
        for (int off = 32; off; off >>= 1) s += __shfl_down(s, off, 64);
        if (lane == 0) redG[w] = s;
        __syncthreads();
        if (tid == 0) {
            float tot = 0.f;
#pragma unroll
            for (int r = 0; r < 8; r++) tot += redG[r];
            gram[((size_t)bb * KK + k) * KK + j] = tot;
            gram[((size_t)bb * KK + j) * KK + k] = tot;
        }
        __syncthreads();
    }
}

// ---------------------------------------------------------------------------
// K_cr (fused combine + readout): grid = bn(32) x ct(16) = 512 blocks, 256 thr.
// Phase A: combine 16 bf16 partials + v_k = gram@state + gates -> nsb (LDS),
//          then bf16 k-major LDS tile nsB[16][72].
// Phase B: readout for this block's 16 c over ALL 4096 hw.
// ---------------------------------------------------------------------------
__global__ __launch_bounds__(256) void k_cr(const short* __restrict__ pbuf,
                                            const float* __restrict__ gram,
                                            const float* __restrict__ state,
                                            const float* __restrict__ betaH,
                                            const float* __restrict__ alphaH,
                                            const short* __restrict__ kbfT,
                                            float* __restrict__ out) {
    const int tid = threadIdx.x;
    const int id = blockIdx.x;        // bn*16 + ct
    const int ct = id & 15;
    const int bn = id >> 4;
    const int b  = bn >> 4;
    const int head = ct >> 1;
    const int wi = ct >> 1, m2 = ct & 1;

    __shared__ float gramL[KK][65];
    __shared__ float stL[KK][17];
    __shared__ float alphaL[KK], betaL[KK];
    __shared__ float nsb[KK][17];
    __shared__ short nsB[16][72];     // bf16, k-contiguous, padded

    for (int i = tid; i < KK * KK; i += 256)
        gramL[i >> 6][i & 63] = gram[(size_t)b * KK * KK + i];
    for (int i = tid; i < KK * 16; i += 256)
        stL[i >> 4][i & 15] = state[((size_t)bn * KK + (i >> 4)) * CC + ct * 16 + (i & 15)];
    if (tid < KK) {
        alphaL[tid] = alphaH[((size_t)bn * KK + tid) * NH + head];
        betaL[tid]  = betaH[((size_t)bn * KK + tid) * NH + head];
    }
    __syncthreads();

    {
        const int k = tid >> 2, cq = (tid & 3) * 4;
        const int n4 = k >> 4, l15k = k & 15, hi4 = tid & 3;

        float vkt[4] = {0.f, 0.f, 0.f, 0.f};
#pragma unroll
        for (int hs = 0; hs < 16; hs++) {
            const int slab = bn * 16 + hs;
            const s16x4 p = *(const s16x4*)(pbuf +
                ((((size_t)(slab * 8 + wi) * 2 + m2) * 4 + n4) * 64 + hi4 * 16 + l15k) * 4);
#pragma unroll
            for (int i = 0; i < 4; i++) vkt[i] += bf2f(p[i]);
        }

        float vk[4] = {0.f, 0.f, 0.f, 0.f};
#pragma unroll 8
        for (int j = 0; j < KK; j++) {
            const float g = gramL[k][j];
            vk[0] = fmaf(g, stL[j][cq + 0], vk[0]);
            vk[1] = fmaf(g, stL[j][cq + 1], vk[1]);
            vk[2] = fmaf(g, stL[j][cq + 2], vk[2]);
            vk[3] = fmaf(g, stL[j][cq + 3], vk[3]);
        }
        const float al = alphaL[k], be = betaL[k];
#pragma unroll
        for (int i = 0; i < 4; i++)
            nsb[k][cq + i] = al * (stL[k][cq + i] - be * vk[i]) + be * vkt[i];
    }
    __syncthreads();

    {   // nsb (f32, [k][c]) -> nsB (bf16, [c][k])
        const int c = tid >> 4, k4 = (tid & 15) * 4;
        s16x4 v;
#pragma unroll
        for (int i = 0; i < 4; i++) v[i] = f2bf(nsb[k4 + i][c]);
        *(s16x4*)&nsB[c][k4] = v;
    }
    __syncthreads();

    // ---------------- phase B: readout ----------------
    const int w = tid >> 6, lane = tid & 63;
    const int l15 = lane & 15, hi = lane >> 4;

    const s16x8 cf0 = *(const s16x8*)&nsB[l15][hi * 8];        // B-frag, k 0..31
    const s16x8 cf1 = *(const s16x8*)&nsB[l15][32 + hi * 8];   // B-frag, k 32..63

    const short* kb = kbfT + ((size_t)b * HW + l15) * KK + hi * 8;
    float* ob = out + ((size_t)bn * CC + ct * 16 + l15) * HW + hi * 4;

#pragma unroll 4
    for (int mt = 0; mt < 64; mt++) {
        const int hw0 = mt * 64 + w * 16;
        const short* Bp = kb + (size_t)hw0 * KK;
        const s16x8 hwf0 = *(const s16x8*)Bp;
        const s16x8 hwf1 = *(const s16x8*)(Bp + 32);
        f32x4 acc = (f32x4){0.f, 0.f, 0.f, 0.f};
        acc = __builtin_amdgcn_mfma_f32_16x16x32_bf16(hwf0, cf0, acc, 0, 0, 0);
        acc = __builtin_amdgcn_mfma_f32_16x16x32_bf16(hwf1, cf1, acc, 0, 0, 0);
        *(f32x4*)(ob + hw0) = acc;
    }
}

// ---------------------------------------------------------------------------
extern "C" void kernel_launch(void* const* d_in, const int* in_sizes, int n_in,
                              void* d_out, int out_size, void* d_ws, size_t ws_size,
                              hipStream_t stream) {
    const float* value   = (const float*)d_in[0];
    const float* key_map = (const float*)d_in[1];
    const float* state   = (const float*)d_in[2];
    const float* b_w     = (const float*)d_in[3];
    const float* a_w     = (const float*)d_in[4];
    const float* A_log   = (const float*)d_in[5];
    const float* dt_bias = (const float*)d_in[6];
    float* out = (float*)d_out;

    short* kbf   = (short*)d_ws;              // B*K*HW bf16     = 524288 sh
    short* kbfT  = kbf + 524288;              // B*HW*K bf16     = 524288 sh
    float* gram  = (float*)(kbfT + 524288);   // B*K*K           =   8192 f32
    float* betaH = gram + 8192;               // B*N*K*NH        =  16384 f32
    float* alphaH= betaH + 16384;             // B*N*K*NH        =  16384 f32
    short* pbufB = (short*)(alphaH + 16384);  // 512*16384 bf16  = 16 MB
    // total ~18.5 MB of d_ws

    k_pre<<<BB * NN * KK + BB * (HW / 128), 256, 0, stream>>>(
        state, b_w, a_w, A_log, dt_bias, betaH, alphaH, key_map, kbf, kbfT);
    k_vkt_part<<<BB * NN * 16, 512, 0, stream>>>(kbf, value, pbufB, gram);
    k_cr<<<BB * NN * 16, 256, 0, stream>>>(pbufB, gram, state, betaH, alphaH,
                                           kbfT, out);
}

// Round 16
// 99.875 us; speedup vs baseline: 5.4059x; 1.0731x over previous
//
#include <hip/hip_runtime.h>
#include <hip/hip_bf16.h>

// Shapes (fixed for this problem)
#define BB 2
#define NN 16
#define CC 256
#define KK 64
#define HW 4096
#define NH 8

typedef __attribute__((ext_vector_type(4))) float f32x4;
typedef __attribute__((ext_vector_type(8))) short s16x8;
typedef __attribute__((ext_vector_type(4))) short s16x4;

__device__ __forceinline__ short f2bf(float f) {
    __hip_bfloat16 h = __float2bfloat16(f);
    return *reinterpret_cast<short*>(&h);
}
__device__ __forceinline__ float bf2f(short s) {
    unsigned int u = ((unsigned int)(unsigned short)s) << 16;
    float f; __builtin_memcpy(&f, &u, 4); return f;
}

// ---------------------------------------------------------------------------
// K1 (fused): blocks [0,2048) = gates (beta/alpha per (b,n,k,h));
//             blocks [2048,2112) = softmax over K (emits kbf, kbfT).
// ---------------------------------------------------------------------------
__global__ __launch_bounds__(256) void k_pre(const float* __restrict__ state,
                                             const float* __restrict__ b_w,
                                             const float* __restrict__ a_w,
                                             const float* __restrict__ A_log,
                                             const float* __restrict__ dt_bias,
                                             float* __restrict__ betaH,
                                             float* __restrict__ alphaH,
                                             const float* __restrict__ km,
                                             short* __restrict__ kbf,
                                             short* __restrict__ kbfT) {
    __shared__ float red[4][2 * NH];
    const int tid = threadIdx.x;
    const int bid = blockIdx.x;

    if (bid < BB * NN * KK) {
        // ---------------- gates ----------------
        const int id = bid;            // (b*N+n)*K + k
        const int bn = id >> 6;
        const int k = id & 63;
        const float s = state[((size_t)bn * KK + k) * CC + tid];

        float pb[NH], pa[NH];
#pragma unroll
        for (int h = 0; h < NH; h++) {
            pb[h] = s * b_w[h * CC + tid];
            pa[h] = s * a_w[h * CC + tid];
        }
#pragma unroll
        for (int off = 32; off; off >>= 1) {
#pragma unroll
            for (int h = 0; h < NH; h++) {
                pb[h] += __shfl_down(pb[h], off, 64);
                pa[h] += __shfl_down(pa[h], off, 64);
            }
        }
        const int wave = tid >> 6, lane = tid & 63;
        if (lane == 0) {
#pragma unroll
            for (int h = 0; h < NH; h++) { red[wave][h] = pb[h]; red[wave][NH + h] = pa[h]; }
        }
        __syncthreads();
        const int h = tid >> 5;
        float braw = 0.f, araw = 0.f;
#pragma unroll
        for (int w = 0; w < 4; w++) { braw += red[w][h]; araw += red[w][NH + h]; }
        if ((tid & 31) == 0) {
            const float beta = 1.f / (1.f + __expf(-braw));
            const float xx = araw + dt_bias[h];
            const float sp = fmaxf(xx, 0.f) + log1pf(__expf(-fabsf(xx)));
            betaH[(size_t)id * NH + h] = beta;
            alphaH[(size_t)id * NH + h] = -__expf(A_log[h]) * sp;
        }
    } else {
        // ---------------- softmax (128 hw per block) ----------------
        const int sid = bid - BB * NN * KK;     // 0..63
        const int b = sid >> 5;                 // 32 blocks per b
        const int w = tid >> 6, lane = tid & 63;
        const int hw = (sid & 31) * 128 + w * 32 + (lane & 31);
        const int half = lane >> 5;             // k in [half*32, half*32+32)
        const float* p = km + ((size_t)b * KK + half * 32) * HW + hw;
        float x[32];
        float m = -1e30f;
#pragma unroll
        for (int k = 0; k < 32; k++) { x[k] = p[(size_t)k * HW]; m = fmaxf(m, x[k]); }
        m = fmaxf(m, __shfl_xor(m, 32, 64));
        float s = 0.f;
#pragma unroll
        for (int k = 0; k < 32; k++) { x[k] = __expf(x[k] - m); s += x[k]; }
        s += __shfl_xor(s, 32, 64);
        const float inv = 1.f / s;
        short* q2 = kbf + ((size_t)b * KK + half * 32) * HW + hw;
#pragma unroll
        for (int k = 0; k < 32; k++) {
            x[k] *= inv;
            q2[(size_t)k * HW] = f2bf(x[k]);
        }
        short* q3 = kbfT + ((size_t)b * HW + hw) * KK + half * 32;
#pragma unroll
        for (int k8 = 0; k8 < 32; k8 += 8) {
            s16x8 v;
#pragma unroll
            for (int j = 0; j < 8; j++) v[j] = f2bf(x[k8 + j]);
            *(s16x8*)(q3 + k8) = v;
        }
    }
}

// ---------------------------------------------------------------------------
// K2: gram[b,k,j] = sum_hw kn[b,k,hw]*kn[b,j,hw]. Symmetric (k>=j, mirror).
// ---------------------------------------------------------------------------
__global__ __launch_bounds__(256) void k_gram(const short* __restrict__ kbf,
                                              float* __restrict__ gram) {
    const int tid = threadIdx.x;
    const int id = blockIdx.x;              // b*2080 + t
    const int b = (id >= 2080) ? 1 : 0;
    const int t = id - b * 2080;
    int k = (int)((sqrtf(8.f * (float)t + 1.f) - 1.f) * 0.5f);
    while ((k + 1) * (k + 2) / 2 <= t) k++;
    while (k * (k + 1) / 2 > t) k--;
    const int j = t - k * (k + 1) / 2;

    const short* pa = kbf + ((size_t)b * KK + k) * HW + tid * 16;
    const short* pb = kbf + ((size_t)b * KK + j) * HW + tid * 16;
    const s16x8 a0 = *(const s16x8*)pa, a1 = *(const s16x8*)(pa + 8);
    const s16x8 b0 = *(const s16x8*)pb, b1 = *(const s16x8*)(pb + 8);
    float s = 0.f;
#pragma unroll
    for (int i = 0; i < 8; i++) {
        s = fmaf(bf2f(a0[i]), bf2f(b0[i]), s);
        s = fmaf(bf2f(a1[i]), bf2f(b1[i]), s);
    }
#pragma unroll
    for (int off = 32; off; off >>= 1) s += __shfl_down(s, off, 64);
    __shared__ float red[4];
    if ((tid & 63) == 0) red[tid >> 6] = s;
    __syncthreads();
    if (tid == 0) {
        const float tot = red[0] + red[1] + red[2] + red[3];
        gram[((size_t)b * KK + k) * KK + j] = tot;
        gram[((size_t)b * KK + j) * KK + k] = tot;
    }
}

// ---------------------------------------------------------------------------
// K4a (MFMA, split-K): partial vkt[k, all 256 c] per 256-hw slab.
// Grid = bn(32) x hs(16) = 512 blocks, 512 threads (8 waves).
// Single barrier per iteration; bf16 partials, store-order-native layout,
// chunk radix 8. (Unchanged from r12/r13 — debugged & passing.)
// ---------------------------------------------------------------------------
__global__ __launch_bounds__(512) void k_vkt_part(const short* __restrict__ kbf,
                                                  const float* __restrict__ value,
                                                  short* __restrict__ pbuf) {
    const int tid = threadIdx.x;
    const int id = blockIdx.x;          // bn*16 + hs
    const int hs = id & 15;
    const int bn = id >> 4;
    const int b  = bn >> 4;
    const int w = tid >> 6, lane = tid & 63;
    const int l15 = lane & 15, hi = lane >> 4;
    const int hw0 = hs * 256;

    __shared__ short Bs[2][256 * 64];   // value tile bf16, 32KB per buffer
    __shared__ short As[2][64 * 64];    // kbf  tile bf16,  8KB per buffer

    const int sr = tid >> 3;            // 0..63
    const int sj = tid & 7;             // 0..7
    const float* vbase = value + (size_t)bn * CC * HW + hw0;
    const short* abase = kbf + ((size_t)b * KK + sr) * HW + hw0 + sj * 8;

    f32x4 stgB[2][4][2];
    s16x8 stgA[2];

#define LOADREG(set_, t_)                                                      \
    {                                                                          \
        _Pragma("unroll") for (int i = 0; i < 4; i++) {                        \
            const float* p_ = vbase + (size_t)(sr + i * 64) * HW               \
                              + (t_) * 64 + sj * 8;                            \
            stgB[set_][i][0] = *(const f32x4*)p_;                              \
            stgB[set_][i][1] = *(const f32x4*)(p_ + 4);                        \
        }                                                                      \
        stgA[set_] = *(const s16x8*)(abase + (t_) * 64);                       \
    }
#define WRITE_LDS(set_, buf_)                                                  \
    {                                                                          \
        _Pragma("unroll") for (int i = 0; i < 4; i++) {                        \
            const int r_ = sr + i * 64;                                        \
            s16x8 tv_;                                                         \
            _Pragma("unroll") for (int e = 0; e < 4; e++) {                    \
                tv_[e]     = f2bf(stgB[set_][i][0][e]);                        \
                tv_[4 + e] = f2bf(stgB[set_][i][1][e]);                        \
            }                                                                  \
            *(s16x8*)&Bs[buf_][r_ * 64 + ((sj ^ (r_ & 7)) * 8)] = tv_;         \
        }                                                                      \
        *(s16x8*)&As[buf_][sr * 64 + ((sj ^ (sr & 7)) * 8)] = stgA[set_];      \
    }

    f32x4 acc[2][4];                    // [c-tile m2][k-tile n4]
#pragma unroll
    for (int m2 = 0; m2 < 2; m2++)
#pragma unroll
        for (int n4 = 0; n4 < 4; n4++) acc[m2][n4] = (f32x4){0.f, 0.f, 0.f, 0.f};

    // prologue
    LOADREG(0, 0);
    LOADREG(1, 1);
    WRITE_LDS(0, 0);
    asm volatile("s_waitcnt lgkmcnt(0)" ::: "memory");
    __builtin_amdgcn_s_barrier();

#pragma unroll
    for (int t = 0; t < 4; t++) {
        const int buf = t & 1;
        if (t + 2 < 4) LOADREG(buf, t + 2);          // HBM prefetch, 2 ahead
        if (t + 1 < 4) WRITE_LDS((t + 1) & 1, (t + 1) & 1);  // stage NEXT buffer

        const int swz = l15 & 7;
#pragma unroll
        for (int s = 0; s < 2; s++) {
            s16x8 vfr[2];
#pragma unroll
            for (int m2 = 0; m2 < 2; m2++)
                vfr[m2] = *(const s16x8*)&Bs[buf][(w * 32 + m2 * 16 + l15) * 64 +
                                                 (((s * 4 + hi) ^ swz) * 8)];
#pragma unroll
            for (int n4 = 0; n4 < 4; n4++) {
                const s16x8 afr = *(const s16x8*)&As[buf][(n4 * 16 + l15) * 64 +
                                                          (((s * 4 + hi) ^ swz) * 8)];
                acc[0][n4] = __builtin_amdgcn_mfma_f32_16x16x32_bf16(vfr[0], afr,
                                                                     acc[0][n4], 0, 0, 0);
                acc[1][n4] = __builtin_amdgcn_mfma_f32_16x16x32_bf16(vfr[1], afr,
                                                                     acc[1][n4], 0, 0, 0);
            }
        }
        if (t + 1 < 4) {
            asm volatile("s_waitcnt lgkmcnt(0)" ::: "memory");
            __builtin_amdgcn_s_barrier();            // single barrier per iter
        }
    }
#undef LOADREG
#undef WRITE_LDS

    // bf16 partial, store-order-native layout, chunk radix 8 (8 waves)
#pragma unroll
    for (int m2 = 0; m2 < 2; m2++)
#pragma unroll
        for (int n4 = 0; n4 < 4; n4++) {
            s16x4 v;
#pragma unroll
            for (int r = 0; r < 4; r++) v[r] = f2bf(acc[m2][n4][r]);
            *(s16x4*)(pbuf + ((((size_t)(id * 8 + w) * 2 + m2) * 4 + n4) * 64
                              + lane) * 4) = v;
        }
}

// ---------------------------------------------------------------------------
// K_cr (fused combine + readout): grid = bn(32) x ct(16) x hh(2) = 1024 blocks.
// Phase A (run redundantly by both hh blocks, L2-resident inputs):
//   combine 16 bf16 partials + v_k = gram@state + gates -> nsb -> bf16 nsB.
// Phase B: readout for this block's 16 c over its hw HALF (2048 hw) ->
//   2x write-TLP (16 waves/CU) vs r13's 512 blocks.
// ---------------------------------------------------------------------------
__global__ __launch_bounds__(256) void k_cr(const short* __restrict__ pbuf,
                                            const float* __restrict__ gram,
                                            const float* __restrict__ state,
                                            const float* __restrict__ betaH,
                                            const float* __restrict__ alphaH,
                                            const short* __restrict__ kbfT,
                                            float* __restrict__ out) {
    const int tid = threadIdx.x;
    const int bid = blockIdx.x;       // (bn*16 + ct)*2 + hh
    const int hh = bid & 1;
    const int id = bid >> 1;          // bn*16 + ct
    const int ct = id & 15;
    const int bn = id >> 4;
    const int b  = bn >> 4;
    const int head = ct >> 1;
    const int wi = ct >> 1, m2 = ct & 1;

    __shared__ float gramL[KK][65];
    __shared__ float stL[KK][17];
    __shared__ float alphaL[KK], betaL[KK];
    __shared__ float nsb[KK][17];
    __shared__ short nsB[16][72];     // bf16, k-contiguous, padded

    for (int i = tid; i < KK * KK; i += 256)
        gramL[i >> 6][i & 63] = gram[(size_t)b * KK * KK + i];
    for (int i = tid; i < KK * 16; i += 256)
        stL[i >> 4][i & 15] = state[((size_t)bn * KK + (i >> 4)) * CC + ct * 16 + (i & 15)];
    if (tid < KK) {
        alphaL[tid] = alphaH[((size_t)bn * KK + tid) * NH + head];
        betaL[tid]  = betaH[((size_t)bn * KK + tid) * NH + head];
    }
    __syncthreads();

    {
        const int k = tid >> 2, cq = (tid & 3) * 4;
        const int n4 = k >> 4, l15k = k & 15, hi4 = tid & 3;

        float vkt[4] = {0.f, 0.f, 0.f, 0.f};
#pragma unroll
        for (int hs = 0; hs < 16; hs++) {
            const int slab = bn * 16 + hs;
            const s16x4 p = *(const s16x4*)(pbuf +
                ((((size_t)(slab * 8 + wi) * 2 + m2) * 4 + n4) * 64 + hi4 * 16 + l15k) * 4);
#pragma unroll
            for (int i = 0; i < 4; i++) vkt[i] += bf2f(p[i]);
        }

        float vk[4] = {0.f, 0.f, 0.f, 0.f};
#pragma unroll 8
        for (int j = 0; j < KK; j++) {
            const float g = gramL[k][j];
            vk[0] = fmaf(g, stL[j][cq + 0], vk[0]);
            vk[1] = fmaf(g, stL[j][cq + 1], vk[1]);
            vk[2] = fmaf(g, stL[j][cq + 2], vk[2]);
            vk[3] = fmaf(g, stL[j][cq + 3], vk[3]);
        }
        const float al = alphaL[k], be = betaL[k];
#pragma unroll
        for (int i = 0; i < 4; i++)
            nsb[k][cq + i] = al * (stL[k][cq + i] - be * vk[i]) + be * vkt[i];
    }
    __syncthreads();

    {   // nsb (f32, [k][c]) -> nsB (bf16, [c][k])
        const int c = tid >> 4, k4 = (tid & 15) * 4;
        s16x4 v;
#pragma unroll
        for (int i = 0; i < 4; i++) v[i] = f2bf(nsb[k4 + i][c]);
        *(s16x4*)&nsB[c][k4] = v;
    }
    __syncthreads();

    // ---------------- phase B: readout (this block's hw half) ----------------
    const int w = tid >> 6, lane = tid & 63;
    const int l15 = lane & 15, hi = lane >> 4;

    const s16x8 cf0 = *(const s16x8*)&nsB[l15][hi * 8];        // B-frag, k 0..31
    const s16x8 cf1 = *(const s16x8*)&nsB[l15][32 + hi * 8];   // B-frag, k 32..63

    const int hwbase = hh * 2048;
    const short* kb = kbfT + ((size_t)b * HW + hwbase + l15) * KK + hi * 8;
    float* ob = out + ((size_t)bn * CC + ct * 16 + l15) * HW + hwbase + hi * 4;

#pragma unroll 4
    for (int mt = 0; mt < 32; mt++) {
        const int hw0 = mt * 64 + w * 16;
        const short* Bp = kb + (size_t)hw0 * KK;
        const s16x8 hwf0 = *(const s16x8*)Bp;
        const s16x8 hwf1 = *(const s16x8*)(Bp + 32);
        f32x4 acc = (f32x4){0.f, 0.f, 0.f, 0.f};
        acc = __builtin_amdgcn_mfma_f32_16x16x32_bf16(hwf0, cf0, acc, 0, 0, 0);
        acc = __builtin_amdgcn_mfma_f32_16x16x32_bf16(hwf1, cf1, acc, 0, 0, 0);
        *(f32x4*)(ob + hw0) = acc;
    }
}

// ---------------------------------------------------------------------------
extern "C" void kernel_launch(void* const* d_in, const int* in_sizes, int n_in,
                              void* d_out, int out_size, void* d_ws, size_t ws_size,
                              hipStream_t stream) {
    const float* value   = (const float*)d_in[0];
    const float* key_map = (const float*)d_in[1];
    const float* state   = (const float*)d_in[2];
    const float* b_w     = (const float*)d_in[3];
    const float* a_w     = (const float*)d_in[4];
    const float* A_log   = (const float*)d_in[5];
    const float* dt_bias = (const float*)d_in[6];
    float* out = (float*)d_out;

    short* kbf   = (short*)d_ws;              // B*K*HW bf16     = 524288 sh
    short* kbfT  = kbf + 524288;              // B*HW*K bf16     = 524288 sh
    float* gram  = (float*)(kbfT + 524288);   // B*K*K           =   8192 f32
    float* betaH = gram + 8192;               // B*N*K*NH        =  16384 f32
    float* alphaH= betaH + 16384;             // B*N*K*NH        =  16384 f32
    short* pbufB = (short*)(alphaH + 16384);  // 512*16384 bf16  = 16 MB
    // total ~18.5 MB of d_ws

    k_pre<<<BB * NN * KK + BB * (HW / 128), 256, 0, stream>>>(
        state, b_w, a_w, A_log, dt_bias, betaH, alphaH, key_map, kbf, kbfT);
    k_gram<<<BB * (KK * (KK + 1) / 2), 256, 0, stream>>>(kbf, gram);
    k_vkt_part<<<BB * NN * 16, 512, 0, stream>>>(kbf, value, pbufB);
    k_cr<<<BB * NN * 16 * 2, 256, 0, stream>>>(pbufB, gram, state, betaH, alphaH,
                                               kbfT, out);
}

// Round 17
// 96.492 us; speedup vs baseline: 5.5954x; 1.0351x over previous
//
#include <hip/hip_runtime.h>
#include <hip/hip_bf16.h>

// Shapes (fixed for this problem)
#define BB 2
#define NN 16
#define CC 256
#define KK 64
#define HW 4096
#define NH 8

typedef __attribute__((ext_vector_type(4))) float f32x4;
typedef __attribute__((ext_vector_type(8))) short s16x8;
typedef __attribute__((ext_vector_type(4))) short s16x4;

__device__ __forceinline__ short f2bf(float f) {
    __hip_bfloat16 h = __float2bfloat16(f);
    return *reinterpret_cast<short*>(&h);
}
__device__ __forceinline__ float bf2f(short s) {
    unsigned int u = ((unsigned int)(unsigned short)s) << 16;
    float f; __builtin_memcpy(&f, &u, 4); return f;
}

// ---------------------------------------------------------------------------
// K1 (fused): blocks [0,2048) = gates (beta/alpha per (b,n,k,h));
//             blocks [2048,2112) = softmax over K (emits kbf, kbfT).
// ---------------------------------------------------------------------------
__global__ __launch_bounds__(256) void k_pre(const float* __restrict__ state,
                                             const float* __restrict__ b_w,
                                             const float* __restrict__ a_w,
                                             const float* __restrict__ A_log,
                                             const float* __restrict__ dt_bias,
                                             float* __restrict__ betaH,
                                             float* __restrict__ alphaH,
                                             const float* __restrict__ km,
                                             short* __restrict__ kbf,
                                             short* __restrict__ kbfT) {
    __shared__ float red[4][2 * NH];
    const int tid = threadIdx.x;
    const int bid = blockIdx.x;

    if (bid < BB * NN * KK) {
        // ---------------- gates ----------------
        const int id = bid;            // (b*N+n)*K + k
        const int bn = id >> 6;
        const int k = id & 63;
        const float s = state[((size_t)bn * KK + k) * CC + tid];

        float pb[NH], pa[NH];
#pragma unroll
        for (int h = 0; h < NH; h++) {
            pb[h] = s * b_w[h * CC + tid];
            pa[h] = s * a_w[h * CC + tid];
        }
#pragma unroll
        for (int off = 32; off; off >>= 1) {
#pragma unroll
            for (int h = 0; h < NH; h++) {
                pb[h] += __shfl_down(pb[h], off, 64);
                pa[h] += __shfl_down(pa[h], off, 64);
            }
        }
        const int wave = tid >> 6, lane = tid & 63;
        if (lane == 0) {
#pragma unroll
            for (int h = 0; h < NH; h++) { red[wave][h] = pb[h]; red[wave][NH + h] = pa[h]; }
        }
        __syncthreads();
        const int h = tid >> 5;
        float braw = 0.f, araw = 0.f;
#pragma unroll
        for (int w = 0; w < 4; w++) { braw += red[w][h]; araw += red[w][NH + h]; }
        if ((tid & 31) == 0) {
            const float beta = 1.f / (1.f + __expf(-braw));
            const float xx = araw + dt_bias[h];
            const float sp = fmaxf(xx, 0.f) + log1pf(__expf(-fabsf(xx)));
            betaH[(size_t)id * NH + h] = beta;
            alphaH[(size_t)id * NH + h] = -__expf(A_log[h]) * sp;
        }
    } else {
        // ---------------- softmax (128 hw per block) ----------------
        const int sid = bid - BB * NN * KK;     // 0..63
        const int b = sid >> 5;                 // 32 blocks per b
        const int w = tid >> 6, lane = tid & 63;
        const int hw = (sid & 31) * 128 + w * 32 + (lane & 31);
        const int half = lane >> 5;             // k in [half*32, half*32+32)
        const float* p = km + ((size_t)b * KK + half * 32) * HW + hw;
        float x[32];
        float m = -1e30f;
#pragma unroll
        for (int k = 0; k < 32; k++) { x[k] = p[(size_t)k * HW]; m = fmaxf(m, x[k]); }
        m = fmaxf(m, __shfl_xor(m, 32, 64));
        float s = 0.f;
#pragma unroll
        for (int k = 0; k < 32; k++) { x[k] = __expf(x[k] - m); s += x[k]; }
        s += __shfl_xor(s, 32, 64);
        const float inv = 1.f / s;
        short* q2 = kbf + ((size_t)b * KK + half * 32) * HW + hw;
#pragma unroll
        for (int k = 0; k < 32; k++) {
            x[k] *= inv;
            q2[(size_t)k * HW] = f2bf(x[k]);
        }
        short* q3 = kbfT + ((size_t)b * HW + hw) * KK + half * 32;
#pragma unroll
        for (int k8 = 0; k8 < 32; k8 += 8) {
            s16x8 v;
#pragma unroll
            for (int j = 0; j < 8; j++) v[j] = f2bf(x[k8 + j]);
            *(s16x8*)(q3 + k8) = v;
        }
    }
}

// ---------------------------------------------------------------------------
// K2: gram[b,k,j] = sum_hw kn[b,k,hw]*kn[b,j,hw]. Symmetric (k>=j, mirror).
// ---------------------------------------------------------------------------
__global__ __launch_bounds__(256) void k_gram(const short* __restrict__ kbf,
                                              float* __restrict__ gram) {
    const int tid = threadIdx.x;
    const int id = blockIdx.x;              // b*2080 + t
    const int b = (id >= 2080) ? 1 : 0;
    const int t = id - b * 2080;
    int k = (int)((sqrtf(8.f * (float)t + 1.f) - 1.f) * 0.5f);
    while ((k + 1) * (k + 2) / 2 <= t) k++;
    while (k * (k + 1) / 2 > t) k--;
    const int j = t - k * (k + 1) / 2;

    const short* pa = kbf + ((size_t)b * KK + k) * HW + tid * 16;
    const short* pb = kbf + ((size_t)b * KK + j) * HW + tid * 16;
    const s16x8 a0 = *(const s16x8*)pa, a1 = *(const s16x8*)(pa + 8);
    const s16x8 b0 = *(const s16x8*)pb, b1 = *(const s16x8*)(pb + 8);
    float s = 0.f;
#pragma unroll
    for (int i = 0; i < 8; i++) {
        s = fmaf(bf2f(a0[i]), bf2f(b0[i]), s);
        s = fmaf(bf2f(a1[i]), bf2f(b1[i]), s);
    }
#pragma unroll
    for (int off = 32; off; off >>= 1) s += __shfl_down(s, off, 64);
    __shared__ float red[4];
    if ((tid & 63) == 0) red[tid >> 6] = s;
    __syncthreads();
    if (tid == 0) {
        const float tot = red[0] + red[1] + red[2] + red[3];
        gram[((size_t)b * KK + k) * KK + j] = tot;
        gram[((size_t)b * KK + j) * KK + k] = tot;
    }
}

// ---------------------------------------------------------------------------
// K4a (MFMA, split-K): partial vkt[k, all 256 c] per 256-hw slab.
// Grid = bn(32) x hs(16) = 512 blocks, 512 threads (8 waves).
// Single barrier per iteration; bf16 partials, store-order-native layout,
// chunk radix 8. (Unchanged from r12/r13 — debugged & passing.)
// ---------------------------------------------------------------------------
__global__ __launch_bounds__(512) void k_vkt_part(const short* __restrict__ kbf,
                                                  const float* __restrict__ value,
                                                  short* __restrict__ pbuf) {
    const int tid = threadIdx.x;
    const int id = blockIdx.x;          // bn*16 + hs
    const int hs = id & 15;
    const int bn = id >> 4;
    const int b  = bn >> 4;
    const int w = tid >> 6, lane = tid & 63;
    const int l15 = lane & 15, hi = lane >> 4;
    const int hw0 = hs * 256;

    __shared__ short Bs[2][256 * 64];   // value tile bf16, 32KB per buffer
    __shared__ short As[2][64 * 64];    // kbf  tile bf16,  8KB per buffer

    const int sr = tid >> 3;            // 0..63
    const int sj = tid & 7;             // 0..7
    const float* vbase = value + (size_t)bn * CC * HW + hw0;
    const short* abase = kbf + ((size_t)b * KK + sr) * HW + hw0 + sj * 8;

    f32x4 stgB[2][4][2];
    s16x8 stgA[2];

#define LOADREG(set_, t_)                                                      \
    {                                                                          \
        _Pragma("unroll") for (int i = 0; i < 4; i++) {                        \
            const float* p_ = vbase + (size_t)(sr + i * 64) * HW               \
                              + (t_) * 64 + sj * 8;                            \
            stgB[set_][i][0] = *(const f32x4*)p_;                              \
            stgB[set_][i][1] = *(const f32x4*)(p_ + 4);                        \
        }                                                                      \
        stgA[set_] = *(const s16x8*)(abase + (t_) * 64);                       \
    }
#define WRITE_LDS(set_, buf_)                                                  \
    {                                                                          \
        _Pragma("unroll") for (int i = 0; i < 4; i++) {                        \
            const int r_ = sr + i * 64;                                        \
            s16x8 tv_;                                                         \
            _Pragma("unroll") for (int e = 0; e < 4; e++) {                    \
                tv_[e]     = f2bf(stgB[set_][i][0][e]);                        \
                tv_[4 + e] = f2bf(stgB[set_][i][1][e]);                        \
            }                                                                  \
            *(s16x8*)&Bs[buf_][r_ * 64 + ((sj ^ (r_ & 7)) * 8)] = tv_;         \
        }                                                                      \
        *(s16x8*)&As[buf_][sr * 64 + ((sj ^ (sr & 7)) * 8)] = stgA[set_];      \
    }

    f32x4 acc[2][4];                    // [c-tile m2][k-tile n4]
#pragma unroll
    for (int m2 = 0; m2 < 2; m2++)
#pragma unroll
        for (int n4 = 0; n4 < 4; n4++) acc[m2][n4] = (f32x4){0.f, 0.f, 0.f, 0.f};

    // prologue
    LOADREG(0, 0);
    LOADREG(1, 1);
    WRITE_LDS(0, 0);
    asm volatile("s_waitcnt lgkmcnt(0)" ::: "memory");
    __builtin_amdgcn_s_barrier();

#pragma unroll
    for (int t = 0; t < 4; t++) {
        const int buf = t & 1;
        if (t + 2 < 4) LOADREG(buf, t + 2);          // HBM prefetch, 2 ahead
        if (t + 1 < 4) WRITE_LDS((t + 1) & 1, (t + 1) & 1);  // stage NEXT buffer

        const int swz = l15 & 7;
#pragma unroll
        for (int s = 0; s < 2; s++) {
            s16x8 vfr[2];
#pragma unroll
            for (int m2 = 0; m2 < 2; m2++)
                vfr[m2] = *(const s16x8*)&Bs[buf][(w * 32 + m2 * 16 + l15) * 64 +
                                                 (((s * 4 + hi) ^ swz) * 8)];
#pragma unroll
            for (int n4 = 0; n4 < 4; n4++) {
                const s16x8 afr = *(const s16x8*)&As[buf][(n4 * 16 + l15) * 64 +
                                                          (((s * 4 + hi) ^ swz) * 8)];
                acc[0][n4] = __builtin_amdgcn_mfma_f32_16x16x32_bf16(vfr[0], afr,
                                                                     acc[0][n4], 0, 0, 0);
                acc[1][n4] = __builtin_amdgcn_mfma_f32_16x16x32_bf16(vfr[1], afr,
                                                                     acc[1][n4], 0, 0, 0);
            }
        }
        if (t + 1 < 4) {
            asm volatile("s_waitcnt lgkmcnt(0)" ::: "memory");
            __builtin_amdgcn_s_barrier();            // single barrier per iter
        }
    }
#undef LOADREG
#undef WRITE_LDS

    // bf16 partial, store-order-native layout, chunk radix 8 (8 waves)
#pragma unroll
    for (int m2 = 0; m2 < 2; m2++)
#pragma unroll
        for (int n4 = 0; n4 < 4; n4++) {
            s16x4 v;
#pragma unroll
            for (int r = 0; r < 4; r++) v[r] = f2bf(acc[m2][n4][r]);
            *(s16x4*)(pbuf + ((((size_t)(id * 8 + w) * 2 + m2) * 4 + n4) * 64
                              + lane) * 4) = v;
        }
}

// ---------------------------------------------------------------------------
// K_cr (fused combine + readout): grid = bn(32) x ct(16) = 512 blocks,
// 512 threads (8 waves). Phase A (combine + gates) runs on tid<256 exactly
// as r13; phase B (readout, the 134MB write stream) uses ALL 8 waves —
// wave w8 covers hw0 = mt*128 + w8*16 (validated in r14's P7) -> 2x
// write-TLP vs r13 with no phase-A duplication.
// ---------------------------------------------------------------------------
__global__ __launch_bounds__(512) void k_cr(const short* __restrict__ pbuf,
                                            const float* __restrict__ gram,
                                            const float* __restrict__ state,
                                            const float* __restrict__ betaH,
                                            const float* __restrict__ alphaH,
                                            const short* __restrict__ kbfT,
                                            float* __restrict__ out) {
    const int tid = threadIdx.x;
    const int id = blockIdx.x;        // bn*16 + ct
    const int ct = id & 15;
    const int bn = id >> 4;
    const int b  = bn >> 4;
    const int head = ct >> 1;
    const int wi = ct >> 1, m2 = ct & 1;

    __shared__ float gramL[KK][65];
    __shared__ float stL[KK][17];
    __shared__ float alphaL[KK], betaL[KK];
    __shared__ float nsb[KK][17];
    __shared__ short nsB[16][72];     // bf16, k-contiguous, padded

    for (int i = tid; i < KK * KK; i += 512)
        gramL[i >> 6][i & 63] = gram[(size_t)b * KK * KK + i];
    for (int i = tid; i < KK * 16; i += 512)
        stL[i >> 4][i & 15] = state[((size_t)bn * KK + (i >> 4)) * CC + ct * 16 + (i & 15)];
    if (tid < KK) {
        alphaL[tid] = alphaH[((size_t)bn * KK + tid) * NH + head];
        betaL[tid]  = betaH[((size_t)bn * KK + tid) * NH + head];
    }
    __syncthreads();

    if (tid < 256) {
        const int k = tid >> 2, cq = (tid & 3) * 4;
        const int n4 = k >> 4, l15k = k & 15, hi4 = tid & 3;

        float vkt[4] = {0.f, 0.f, 0.f, 0.f};
#pragma unroll
        for (int hs = 0; hs < 16; hs++) {
            const int slab = bn * 16 + hs;
            const s16x4 p = *(const s16x4*)(pbuf +
                ((((size_t)(slab * 8 + wi) * 2 + m2) * 4 + n4) * 64 + hi4 * 16 + l15k) * 4);
#pragma unroll
            for (int i = 0; i < 4; i++) vkt[i] += bf2f(p[i]);
        }

        float vk[4] = {0.f, 0.f, 0.f, 0.f};
#pragma unroll 8
        for (int j = 0; j < KK; j++) {
            const float g = gramL[k][j];
            vk[0] = fmaf(g, stL[j][cq + 0], vk[0]);
            vk[1] = fmaf(g, stL[j][cq + 1], vk[1]);
            vk[2] = fmaf(g, stL[j][cq + 2], vk[2]);
            vk[3] = fmaf(g, stL[j][cq + 3], vk[3]);
        }
        const float al = alphaL[k], be = betaL[k];
#pragma unroll
        for (int i = 0; i < 4; i++)
            nsb[k][cq + i] = al * (stL[k][cq + i] - be * vk[i]) + be * vkt[i];
    }
    __syncthreads();

    if (tid < 256) {   // nsb (f32, [k][c]) -> nsB (bf16, [c][k])
        const int c = tid >> 4, k4 = (tid & 15) * 4;
        s16x4 v;
#pragma unroll
        for (int i = 0; i < 4; i++) v[i] = f2bf(nsb[k4 + i][c]);
        *(s16x4*)&nsB[c][k4] = v;
    }
    __syncthreads();

    // ---------------- phase B: readout, all 8 waves ----------------
    const int w8 = tid >> 6, lane = tid & 63;
    const int l15 = lane & 15, hi = lane >> 4;

    const s16x8 cf0 = *(const s16x8*)&nsB[l15][hi * 8];        // B-frag, k 0..31
    const s16x8 cf1 = *(const s16x8*)&nsB[l15][32 + hi * 8];   // B-frag, k 32..63

    const short* kb = kbfT + ((size_t)b * HW + l15) * KK + hi * 8;
    float* ob = out + ((size_t)bn * CC + ct * 16 + l15) * HW + hi * 4;

#pragma unroll 4
    for (int mt = 0; mt < 32; mt++) {
        const int hw0 = mt * 128 + w8 * 16;
        const short* Bp = kb + (size_t)hw0 * KK;
        const s16x8 hwf0 = *(const s16x8*)Bp;
        const s16x8 hwf1 = *(const s16x8*)(Bp + 32);
        f32x4 acc = (f32x4){0.f, 0.f, 0.f, 0.f};
        acc = __builtin_amdgcn_mfma_f32_16x16x32_bf16(hwf0, cf0, acc, 0, 0, 0);
        acc = __builtin_amdgcn_mfma_f32_16x16x32_bf16(hwf1, cf1, acc, 0, 0, 0);
        *(f32x4*)(ob + hw0) = acc;
    }
}

// ---------------------------------------------------------------------------
extern "C" void kernel_launch(void* const* d_in, const int* in_sizes, int n_in,
                              void* d_out, int out_size, void* d_ws, size_t ws_size,
                              hipStream_t stream) {
    const float* value   = (const float*)d_in[0];
    const float* key_map = (const float*)d_in[1];
    const float* state   = (const float*)d_in[2];
    const float* b_w     = (const float*)d_in[3];
    const float* a_w     = (const float*)d_in[4];
    const float* A_log   = (const float*)d_in[5];
    const float* dt_bias = (const float*)d_in[6];
    float* out = (float*)d_out;

    short* kbf   = (short*)d_ws;              // B*K*HW bf16     = 524288 sh
    short* kbfT  = kbf + 524288;              // B*HW*K bf16     = 524288 sh
    float* gram  = (float*)(kbfT + 524288);   // B*K*K           =   8192 f32
    float* betaH = gram + 8192;               // B*N*K*NH        =  16384 f32
    float* alphaH= betaH + 16384;             // B*N*K*NH        =  16384 f32
    short* pbufB = (short*)(alphaH + 16384);  // 512*16384 bf16  = 16 MB
    // total ~18.5 MB of d_ws

    k_pre<<<BB * NN * KK + BB * (HW / 128), 256, 0, stream>>>(
        state, b_w, a_w, A_log, dt_bias, betaH, alphaH, key_map, kbf, kbfT);
    k_gram<<<BB * (KK * (KK + 1) / 2), 256, 0, stream>>>(kbf, gram);
    k_vkt_part<<<BB * NN * 16, 512, 0, stream>>>(kbf, value, pbufB);
    k_cr<<<BB * NN * 16, 512, 0, stream>>>(pbufB, gram, state, betaH, alphaH,
                                           kbfT, out);
}

// Round 18
// 92.520 us; speedup vs baseline: 5.8356x; 1.0429x over previous
//
#include <hip/hip_runtime.h>
#include <hip/hip_bf16.h>

// Shapes (fixed for this problem)
#define BB 2
#define NN 16
#define CC 256
#define KK 64
#define HW 4096
#define NH 8

typedef __attribute__((ext_vector_type(4))) float f32x4;
typedef __attribute__((ext_vector_type(8))) short s16x8;
typedef __attribute__((ext_vector_type(4))) short s16x4;

__device__ __forceinline__ short f2bf(float f) {
    __hip_bfloat16 h = __float2bfloat16(f);
    return *reinterpret_cast<short*>(&h);
}
__device__ __forceinline__ float bf2f(short s) {
    unsigned int u = ((unsigned int)(unsigned short)s) << 16;
    float f; __builtin_memcpy(&f, &u, 4); return f;
}

// ---------------------------------------------------------------------------
// K1 (fused): blocks [0,2048) = gates (beta/alpha per (b,n,k,h));
//             blocks [2048,2112) = softmax over K (emits kbf, kbfT).
// ---------------------------------------------------------------------------
__global__ __launch_bounds__(256) void k_pre(const float* __restrict__ state,
                                             const float* __restrict__ b_w,
                                             const float* __restrict__ a_w,
                                             const float* __restrict__ A_log,
                                             const float* __restrict__ dt_bias,
                                             float* __restrict__ betaH,
                                             float* __restrict__ alphaH,
                                             const float* __restrict__ km,
                                             short* __restrict__ kbf,
                                             short* __restrict__ kbfT) {
    __shared__ float red[4][2 * NH];
    const int tid = threadIdx.x;
    const int bid = blockIdx.x;

    if (bid < BB * NN * KK) {
        // ---------------- gates ----------------
        const int id = bid;            // (b*N+n)*K + k
        const int bn = id >> 6;
        const int k = id & 63;
        const float s = state[((size_t)bn * KK + k) * CC + tid];

        float pb[NH], pa[NH];
#pragma unroll
        for (int h = 0; h < NH; h++) {
            pb[h] = s * b_w[h * CC + tid];
            pa[h] = s * a_w[h * CC + tid];
        }
#pragma unroll
        for (int off = 32; off; off >>= 1) {
#pragma unroll
            for (int h = 0; h < NH; h++) {
                pb[h] += __shfl_down(pb[h], off, 64);
                pa[h] += __shfl_down(pa[h], off, 64);
            }
        }
        const int wave = tid >> 6, lane = tid & 63;
        if (lane == 0) {
#pragma unroll
            for (int h = 0; h < NH; h++) { red[wave][h] = pb[h]; red[wave][NH + h] = pa[h]; }
        }
        __syncthreads();
        const int h = tid >> 5;
        float braw = 0.f, araw = 0.f;
#pragma unroll
        for (int w = 0; w < 4; w++) { braw += red[w][h]; araw += red[w][NH + h]; }
        if ((tid & 31) == 0) {
            const float beta = 1.f / (1.f + __expf(-braw));
            const float xx = araw + dt_bias[h];
            const float sp = fmaxf(xx, 0.f) + log1pf(__expf(-fabsf(xx)));
            betaH[(size_t)id * NH + h] = beta;
            alphaH[(size_t)id * NH + h] = -__expf(A_log[h]) * sp;
        }
    } else {
        // ---------------- softmax (128 hw per block) ----------------
        const int sid = bid - BB * NN * KK;     // 0..63
        const int b = sid >> 5;                 // 32 blocks per b
        const int w = tid >> 6, lane = tid & 63;
        const int hw = (sid & 31) * 128 + w * 32 + (lane & 31);
        const int half = lane >> 5;             // k in [half*32, half*32+32)
        const float* p = km + ((size_t)b * KK + half * 32) * HW + hw;
        float x[32];
        float m = -1e30f;
#pragma unroll
        for (int k = 0; k < 32; k++) { x[k] = p[(size_t)k * HW]; m = fmaxf(m, x[k]); }
        m = fmaxf(m, __shfl_xor(m, 32, 64));
        float s = 0.f;
#pragma unroll
        for (int k = 0; k < 32; k++) { x[k] = __expf(x[k] - m); s += x[k]; }
        s += __shfl_xor(s, 32, 64);
        const float inv = 1.f / s;
        short* q2 = kbf + ((size_t)b * KK + half * 32) * HW + hw;
#pragma unroll
        for (int k = 0; k < 32; k++) {
            x[k] *= inv;
            q2[(size_t)k * HW] = f2bf(x[k]);
        }
        short* q3 = kbfT + ((size_t)b * HW + hw) * KK + half * 32;
#pragma unroll
        for (int k8 = 0; k8 < 32; k8 += 8) {
            s16x8 v;
#pragma unroll
            for (int j = 0; j < 8; j++) v[j] = f2bf(x[k8 + j]);
            *(s16x8*)(q3 + k8) = v;
        }
    }
}

// ---------------------------------------------------------------------------
// K2: gram[b,k,j] = sum_hw kn[b,k,hw]*kn[b,j,hw]. Symmetric (k>=j, mirror).
// ---------------------------------------------------------------------------
__global__ __launch_bounds__(256) void k_gram(const short* __restrict__ kbf,
                                              float* __restrict__ gram) {
    const int tid = threadIdx.x;
    const int id = blockIdx.x;              // b*2080 + t
    const int b = (id >= 2080) ? 1 : 0;
    const int t = id - b * 2080;
    int k = (int)((sqrtf(8.f * (float)t + 1.f) - 1.f) * 0.5f);
    while ((k + 1) * (k + 2) / 2 <= t) k++;
    while (k * (k + 1) / 2 > t) k--;
    const int j = t - k * (k + 1) / 2;

    const short* pa = kbf + ((size_t)b * KK + k) * HW + tid * 16;
    const short* pb = kbf + ((size_t)b * KK + j) * HW + tid * 16;
    const s16x8 a0 = *(const s16x8*)pa, a1 = *(const s16x8*)(pa + 8);
    const s16x8 b0 = *(const s16x8*)pb, b1 = *(const s16x8*)(pb + 8);
    float s = 0.f;
#pragma unroll
    for (int i = 0; i < 8; i++) {
        s = fmaf(bf2f(a0[i]), bf2f(b0[i]), s);
        s = fmaf(bf2f(a1[i]), bf2f(b1[i]), s);
    }
#pragma unroll
    for (int off = 32; off; off >>= 1) s += __shfl_down(s, off, 64);
    __shared__ float red[4];
    if ((tid & 63) == 0) red[tid >> 6] = s;
    __syncthreads();
    if (tid == 0) {
        const float tot = red[0] + red[1] + red[2] + red[3];
        gram[((size_t)b * KK + k) * KK + j] = tot;
        gram[((size_t)b * KK + j) * KK + k] = tot;
    }
}

// ---------------------------------------------------------------------------
// K4a (MFMA, split-K): partial vkt[k, all 256 c] per 256-hw slab.
// Grid = bn(32) x hs(16) = 512 blocks, 512 threads (8 waves).
// Single barrier per iteration; bf16 partials, store-order-native layout,
// chunk radix 8. (Unchanged from r12/r13 — debugged & passing.)
// ---------------------------------------------------------------------------
__global__ __launch_bounds__(512) void k_vkt_part(const short* __restrict__ kbf,
                                                  const float* __restrict__ value,
                                                  short* __restrict__ pbuf) {
    const int tid = threadIdx.x;
    const int id = blockIdx.x;          // bn*16 + hs
    const int hs = id & 15;
    const int bn = id >> 4;
    const int b  = bn >> 4;
    const int w = tid >> 6, lane = tid & 63;
    const int l15 = lane & 15, hi = lane >> 4;
    const int hw0 = hs * 256;

    __shared__ short Bs[2][256 * 64];   // value tile bf16, 32KB per buffer
    __shared__ short As[2][64 * 64];    // kbf  tile bf16,  8KB per buffer

    const int sr = tid >> 3;            // 0..63
    const int sj = tid & 7;             // 0..7
    const float* vbase = value + (size_t)bn * CC * HW + hw0;
    const short* abase = kbf + ((size_t)b * KK + sr) * HW + hw0 + sj * 8;

    f32x4 stgB[2][4][2];
    s16x8 stgA[2];

#define LOADREG(set_, t_)                                                      \
    {                                                                          \
        _Pragma("unroll") for (int i = 0; i < 4; i++) {                        \
            const float* p_ = vbase + (size_t)(sr + i * 64) * HW               \
                              + (t_) * 64 + sj * 8;                            \
            stgB[set_][i][0] = *(const f32x4*)p_;                              \
            stgB[set_][i][1] = *(const f32x4*)(p_ + 4);                        \
        }                                                                      \
        stgA[set_] = *(const s16x8*)(abase + (t_) * 64);                       \
    }
#define WRITE_LDS(set_, buf_)                                                  \
    {                                                                          \
        _Pragma("unroll") for (int i = 0; i < 4; i++) {                        \
            const int r_ = sr + i * 64;                                        \
            s16x8 tv_;                                                         \
            _Pragma("unroll") for (int e = 0; e < 4; e++) {                    \
                tv_[e]     = f2bf(stgB[set_][i][0][e]);                        \
                tv_[4 + e] = f2bf(stgB[set_][i][1][e]);                        \
            }                                                                  \
            *(s16x8*)&Bs[buf_][r_ * 64 + ((sj ^ (r_ & 7)) * 8)] = tv_;         \
        }                                                                      \
        *(s16x8*)&As[buf_][sr * 64 + ((sj ^ (sr & 7)) * 8)] = stgA[set_];      \
    }

    f32x4 acc[2][4];                    // [c-tile m2][k-tile n4]
#pragma unroll
    for (int m2 = 0; m2 < 2; m2++)
#pragma unroll
        for (int n4 = 0; n4 < 4; n4++) acc[m2][n4] = (f32x4){0.f, 0.f, 0.f, 0.f};

    // prologue
    LOADREG(0, 0);
    LOADREG(1, 1);
    WRITE_LDS(0, 0);
    asm volatile("s_waitcnt lgkmcnt(0)" ::: "memory");
    __builtin_amdgcn_s_barrier();

#pragma unroll
    for (int t = 0; t < 4; t++) {
        const int buf = t & 1;
        if (t + 2 < 4) LOADREG(buf, t + 2);          // HBM prefetch, 2 ahead
        if (t + 1 < 4) WRITE_LDS((t + 1) & 1, (t + 1) & 1);  // stage NEXT buffer

        const int swz = l15 & 7;
#pragma unroll
        for (int s = 0; s < 2; s++) {
            s16x8 vfr[2];
#pragma unroll
            for (int m2 = 0; m2 < 2; m2++)
                vfr[m2] = *(const s16x8*)&Bs[buf][(w * 32 + m2 * 16 + l15) * 64 +
                                                 (((s * 4 + hi) ^ swz) * 8)];
#pragma unroll
            for (int n4 = 0; n4 < 4; n4++) {
                const s16x8 afr = *(const s16x8*)&As[buf][(n4 * 16 + l15) * 64 +
                                                          (((s * 4 + hi) ^ swz) * 8)];
                acc[0][n4] = __builtin_amdgcn_mfma_f32_16x16x32_bf16(vfr[0], afr,
                                                                     acc[0][n4], 0, 0, 0);
                acc[1][n4] = __builtin_amdgcn_mfma_f32_16x16x32_bf16(vfr[1], afr,
                                                                     acc[1][n4], 0, 0, 0);
            }
        }
        if (t + 1 < 4) {
            asm volatile("s_waitcnt lgkmcnt(0)" ::: "memory");
            __builtin_amdgcn_s_barrier();            // single barrier per iter
        }
    }
#undef LOADREG
#undef WRITE_LDS

    // bf16 partial, store-order-native layout, chunk radix 8 (8 waves)
#pragma unroll
    for (int m2 = 0; m2 < 2; m2++)
#pragma unroll
        for (int n4 = 0; n4 < 4; n4++) {
            s16x4 v;
#pragma unroll
            for (int r = 0; r < 4; r++) v[r] = f2bf(acc[m2][n4][r]);
            *(s16x4*)(pbuf + ((((size_t)(id * 8 + w) * 2 + m2) * 4 + n4) * 64
                              + lane) * 4) = v;
        }
}

// ---------------------------------------------------------------------------
// K_cr (fused combine + readout): grid = bn(32) x ct(16) = 512 blocks,
// 512 threads (8 waves). Phase A (combine + gates) on tid<256 (r13/r17).
// Phase B: per outer iter (256 hw x 16 c): wave w8 computes its 32-hw strip
// (4 MFMA), stages acc into a double-buffered f32 LDS tile [16][260], then
// stores with wave = one c-row: 64 lanes x f32x4 = 1KB FULLY CONTIGUOUS per
// store instruction (vs 16 rows x 64B scattered before). One barrier/iter.
// ---------------------------------------------------------------------------
__global__ __launch_bounds__(512) void k_cr(const short* __restrict__ pbuf,
                                            const float* __restrict__ gram,
                                            const float* __restrict__ state,
                                            const float* __restrict__ betaH,
                                            const float* __restrict__ alphaH,
                                            const short* __restrict__ kbfT,
                                            float* __restrict__ out) {
    const int tid = threadIdx.x;
    const int id = blockIdx.x;        // bn*16 + ct
    const int ct = id & 15;
    const int bn = id >> 4;
    const int b  = bn >> 4;
    const int head = ct >> 1;
    const int wi = ct >> 1, m2 = ct & 1;

    __shared__ float gramL[KK][65];
    __shared__ float stL[KK][17];
    __shared__ float alphaL[KK], betaL[KK];
    __shared__ float nsb[KK][17];
    __shared__ short nsB[16][72];       // bf16, k-contiguous, padded
    __shared__ float osb[2][16][260];   // store-transpose tile, 2-way banks

    for (int i = tid; i < KK * KK; i += 512)
        gramL[i >> 6][i & 63] = gram[(size_t)b * KK * KK + i];
    for (int i = tid; i < KK * 16; i += 512)
        stL[i >> 4][i & 15] = state[((size_t)bn * KK + (i >> 4)) * CC + ct * 16 + (i & 15)];
    if (tid < KK) {
        alphaL[tid] = alphaH[((size_t)bn * KK + tid) * NH + head];
        betaL[tid]  = betaH[((size_t)bn * KK + tid) * NH + head];
    }
    __syncthreads();

    if (tid < 256) {
        const int k = tid >> 2, cq = (tid & 3) * 4;
        const int n4 = k >> 4, l15k = k & 15, hi4 = tid & 3;

        float vkt[4] = {0.f, 0.f, 0.f, 0.f};
#pragma unroll
        for (int hs = 0; hs < 16; hs++) {
            const int slab = bn * 16 + hs;
            const s16x4 p = *(const s16x4*)(pbuf +
                ((((size_t)(slab * 8 + wi) * 2 + m2) * 4 + n4) * 64 + hi4 * 16 + l15k) * 4);
#pragma unroll
            for (int i = 0; i < 4; i++) vkt[i] += bf2f(p[i]);
        }

        float vk[4] = {0.f, 0.f, 0.f, 0.f};
#pragma unroll 8
        for (int j = 0; j < KK; j++) {
            const float g = gramL[k][j];
            vk[0] = fmaf(g, stL[j][cq + 0], vk[0]);
            vk[1] = fmaf(g, stL[j][cq + 1], vk[1]);
            vk[2] = fmaf(g, stL[j][cq + 2], vk[2]);
            vk[3] = fmaf(g, stL[j][cq + 3], vk[3]);
        }
        const float al = alphaL[k], be = betaL[k];
#pragma unroll
        for (int i = 0; i < 4; i++)
            nsb[k][cq + i] = al * (stL[k][cq + i] - be * vk[i]) + be * vkt[i];
    }
    __syncthreads();

    if (tid < 256) {   // nsb (f32, [k][c]) -> nsB (bf16, [c][k])
        const int c = tid >> 4, k4 = (tid & 15) * 4;
        s16x4 v;
#pragma unroll
        for (int i = 0; i < 4; i++) v[i] = f2bf(nsb[k4 + i][c]);
        *(s16x4*)&nsB[c][k4] = v;
    }
    __syncthreads();

    // ---------------- phase B: readout with LDS store-transpose ----------------
    const int w8 = tid >> 6, lane = tid & 63;
    const int l15 = lane & 15, hi = lane >> 4;

    const s16x8 cf0 = *(const s16x8*)&nsB[l15][hi * 8];        // B-frag, k 0..31
    const s16x8 cf1 = *(const s16x8*)&nsB[l15][32 + hi * 8];   // B-frag, k 32..63

    const short* kb = kbfT + ((size_t)b * HW + l15) * KK + hi * 8;
    const int sc = tid >> 6;            // store row c (0..7, +8 second pass)
    const int sch = tid & 63;           // store chunk (x f32x4)
    float* orow0 = out + ((size_t)bn * CC + ct * 16 + sc) * HW;
    float* orow1 = out + ((size_t)bn * CC + ct * 16 + sc + 8) * HW;

#pragma unroll 2
    for (int it = 0; it < 16; ++it) {   // 256 hw per iter
        const int hwb = it * 256;
        const int pb = it & 1;
#pragma unroll
        for (int t = 0; t < 2; ++t) {
            const int hw0 = hwb + w8 * 32 + t * 16;
            const short* Bp = kb + (size_t)hw0 * KK;
            const s16x8 hwf0 = *(const s16x8*)Bp;
            const s16x8 hwf1 = *(const s16x8*)(Bp + 32);
            f32x4 acc = (f32x4){0.f, 0.f, 0.f, 0.f};
            acc = __builtin_amdgcn_mfma_f32_16x16x32_bf16(hwf0, cf0, acc, 0, 0, 0);
            acc = __builtin_amdgcn_mfma_f32_16x16x32_bf16(hwf1, cf1, acc, 0, 0, 0);
            // D: col = l15 = c, row = hi*4+r = hw offset within 16-hw tile
            *(f32x4*)&osb[pb][l15][w8 * 32 + t * 16 + hi * 4] = acc;
        }
        __syncthreads();                // osb[pb] complete; prev readers done
        const f32x4 v0 = *(const f32x4*)&osb[pb][sc][sch * 4];
        const f32x4 v1 = *(const f32x4*)&osb[pb][sc + 8][sch * 4];
        *(f32x4*)&orow0[hwb + sch * 4] = v0;   // 1KB contiguous per wave
        *(f32x4*)&orow1[hwb + sch * 4] = v1;
    }
}

// ---------------------------------------------------------------------------
extern "C" void kernel_launch(void* const* d_in, const int* in_sizes, int n_in,
                              void* d_out, int out_size, void* d_ws, size_t ws_size,
                              hipStream_t stream) {
    const float* value   = (const float*)d_in[0];
    const float* key_map = (const float*)d_in[1];
    const float* state   = (const float*)d_in[2];
    const float* b_w     = (const float*)d_in[3];
    const float* a_w     = (const float*)d_in[4];
    const float* A_log   = (const float*)d_in[5];
    const float* dt_bias = (const float*)d_in[6];
    float* out = (float*)d_out;

    short* kbf   = (short*)d_ws;              // B*K*HW bf16     = 524288 sh
    short* kbfT  = kbf + 524288;              // B*HW*K bf16     = 524288 sh
    float* gram  = (float*)(kbfT + 524288);   // B*K*K           =   8192 f32
    float* betaH = gram + 8192;               // B*N*K*NH        =  16384 f32
    float* alphaH= betaH + 16384;             // B*N*K*NH        =  16384 f32
    short* pbufB = (short*)(alphaH + 16384);  // 512*16384 bf16  = 16 MB
    // total ~18.5 MB of d_ws

    k_pre<<<BB * NN * KK + BB * (HW / 128), 256, 0, stream>>>(
        state, b_w, a_w, A_log, dt_bias, betaH, alphaH, key_map, kbf, kbfT);
    k_gram<<<BB * (KK * (KK + 1) / 2), 256, 0, stream>>>(kbf, gram);
    k_vkt_part<<<BB * NN * 16, 512, 0, stream>>>(kbf, value, pbufB);
    k_cr<<<BB * NN * 16, 512, 0, stream>>>(pbufB, gram, state, betaH, alphaH,
                                           kbfT, out);
}